// Round 7
// baseline (390.290 us; speedup 1.0000x reference)
//
#include <hip/hip_runtime.h>
#include <hip/hip_bf16.h>
#include <stdint.h>

typedef __hip_bfloat16 bf16;
typedef __attribute__((ext_vector_type(8))) short s16x8;
typedef __attribute__((ext_vector_type(4))) float f32x4;

#define B_   2
#define S_   2048
#define D_   1024
#define H_   16
#define HD_  64
#define FFD_ 4096
#define M_   4096
#define MEG  ((size_t)1048576)

__device__ __forceinline__ f32x4 mfma_bf16(s16x8 a, s16x8 b, f32x4 c) {
  return __builtin_amdgcn_mfma_f32_16x16x32_bf16(a, b, c, 0, 0, 0);
}

__device__ __forceinline__ void gl_lds16(const bf16* g, bf16* l) {
  __builtin_amdgcn_global_load_lds(
      (const __attribute__((address_space(1))) void*)g,
      (__attribute__((address_space(3))) void*)l, 16, 0, 0);
}

__device__ __forceinline__ float b2f(short u) {
  union { uint32_t i; float f; } z;
  z.i = ((uint32_t)(unsigned short)u) << 16;
  return z.f;
}
__device__ __forceinline__ short f2b(float f) {
  const bf16 h = __float2bfloat16(f);
  return *(const short*)&h;
}

// ---------------------------------------------------------------------------
// fp32 -> bf16 conversion, all 5 tensors in ONE dispatch (z-indexed).
// ---------------------------------------------------------------------------
struct CvtArgs {
  const float* src[5];
  bf16* dst[5];
  int n[5];
};
__global__ __launch_bounds__(256) void cvt_f2b_multi(CvtArgs a) {
  const int z = blockIdx.y;
  const int idx = (blockIdx.x * 256 + threadIdx.x) * 8;
  if (idx >= a.n[z]) return;
  const float* src = a.src[z];
  s16x8 o;
#pragma unroll
  for (int i = 0; i < 8; ++i) o[i] = f2b(src[idx + i]);
  *(s16x8*)(a.dst[z] + idx) = o;
}

// ---------------------------------------------------------------------------
// MFMA NT GEMM: C[m,n] = sum_k A[m,k]*W[n,k] + bias[n]  (bias fp32)
// 128x128 tile, BK=32, 4 waves (2x2), 4x4 16x16x32 frags.
// v3 (round 6, kept): 3-buffer depth-2 counted-vmcnt pipeline (T4);
// T2 chunk-XOR swizzle (linear gl_lds dest + pre-swizzled source);
// T5 setprio; T1 XCD-chunked block swizzle.
// MODE 0: C -> bf16 Cb             (out-proj -> y1)
// MODE 1: relu, C -> bf16 Cb       (MLP1 -> ff)
// MODE 2: SPLIT-K=2 (gridDim.z=2). z=0: K-half-0 + bias + resid -> fp32 Cf.
//         z=1: K-half-1 raw partial -> fp32 Kf (rows<2048) / Vf (rows>=2048).
// MODE 3: QKV split: seg0 q*0.125 -> bf16 Cb (pre-scaled for attn);
//         seg1 k->fp32 Kf + bf16 Kb; seg2 v->fp32 Vf + bf16 Vb.
// ---------------------------------------------------------------------------
template <int MODE>
__global__ __launch_bounds__(256) void gemm_bt(
    const bf16* __restrict__ A, const bf16* __restrict__ W,
    const float* __restrict__ bias,
    bf16* __restrict__ Cb, float* __restrict__ Cf,
    float* __restrict__ Kf, bf16* __restrict__ Kb,
    float* __restrict__ Vf, bf16* __restrict__ Vb,
    const bf16* __restrict__ Res,
    int M, int N, int K) {
  __shared__ __align__(16) bf16 As[3][128 * 32];
  __shared__ __align__(16) bf16 Bs[3][128 * 32];
  const int t = threadIdx.x;

  // T1 XCD-chunked swizzle (all grids have nwg % 8 == 0 -> bijective).
  const int nwg = gridDim.x * gridDim.y;
  const int bid = blockIdx.y * gridDim.x + blockIdx.x;
  const int sw  = (bid & 7) * (nwg >> 3) + (bid >> 3);
  const int m0 = (sw / gridDim.x) << 7, n0 = (sw % gridDim.x) << 7;

  const int w = t >> 6, l = t & 63;
  const int wm = (w >> 1) << 6, wn = (w & 1) << 6;
  const int l15 = l & 15, quad = l >> 4;

  const int kz   = (MODE == 2) ? (int)blockIdx.z : 0;   // K-split index
  const int Keff = (MODE == 2) ? (K >> 1) : K;

  f32x4 acc[4][4] = {};

  // staging: thread t -> LDS row t>>2, phys chunk t&3 (linear dest).
  // source column chunk = phys ^ s(row), s(r) = (r&3)^((r>>2)&3).
  const int srow = t >> 2;          // 0..63
  const int sxs  = (srow & 3) ^ ((srow >> 2) & 3);
  const int scol = ((t & 3) ^ sxs) << 3;
  const bf16* Ag  = A + (size_t)(m0 + srow) * K + kz * Keff + scol;
  const bf16* Ag2 = Ag + ((size_t)K << 6);   // +64 rows: s(row) unchanged
  const bf16* Wg  = W + (size_t)(n0 + srow) * K + kz * Keff + scol;
  const bf16* Wg2 = Wg + ((size_t)K << 6);

#define STAGE_G(KI, BUF) do {                                                \
    bf16* Ad_ = (bf16*)As[BUF] + t * 8;                                      \
    bf16* Bd_ = (bf16*)Bs[BUF] + t * 8;                                      \
    const int ko_ = (KI) << 5;                                               \
    gl_lds16(Ag + ko_, Ad_);                                                 \
    gl_lds16(Ag2 + ko_, Ad_ + 2048);                                         \
    gl_lds16(Wg + ko_, Bd_);                                                 \
    gl_lds16(Wg2 + ko_, Bd_ + 2048);                                         \
  } while (0)

  const int nk = Keff >> 5;
  STAGE_G(0, 0);
  STAGE_G(1, 1);

  // read-side swizzle term: s(row) depends only on l15 (wm, i*16 drop out).
  const int sxr = (l15 & 3) ^ ((l15 >> 2) & 3);
  const int arow = (wm + l15) << 2;     // frag i adds i*64
  const int brow = (wn + l15) << 2;

  int cur = 0;
  for (int ki = 0; ki < nk; ++ki) {
    asm volatile("s_waitcnt lgkmcnt(0)" ::: "memory");
    __builtin_amdgcn_s_barrier();
    __builtin_amdgcn_sched_barrier(0);
    if (ki + 2 < nk) {
      const int nb = cur ? cur - 1 : 2;      // (cur+2)%3
      STAGE_G(ki + 2, nb);
      asm volatile("s_waitcnt vmcnt(8)" ::: "memory");   // stage(ki) landed
    } else if (ki + 1 < nk) {
      asm volatile("s_waitcnt vmcnt(4)" ::: "memory");
    } else {
      asm volatile("s_waitcnt vmcnt(0)" ::: "memory");
    }
    __builtin_amdgcn_sched_barrier(0);

    const s16x8* As8 = (const s16x8*)As[cur];
    const s16x8* Bs8 = (const s16x8*)Bs[cur];
    const int cq = quad ^ sxr;
    s16x8 af[4], bfr[4];
#pragma unroll
    for (int i = 0; i < 4; ++i) af[i]  = As8[arow + (i << 6) + cq];
#pragma unroll
    for (int i = 0; i < 4; ++i) bfr[i] = Bs8[brow + (i << 6) + cq];
    __builtin_amdgcn_s_setprio(1);
#pragma unroll
    for (int mi = 0; mi < 4; ++mi)
#pragma unroll
      for (int ni = 0; ni < 4; ++ni)
        acc[mi][ni] = mfma_bf16(af[mi], bfr[ni], acc[mi][ni]);
    __builtin_amdgcn_s_setprio(0);
    cur = (cur == 2) ? 0 : cur + 1;
  }
#undef STAGE_G

  float bv[4];
#pragma unroll
  for (int ni = 0; ni < 4; ++ni)
    bv[ni] = bias[n0 + wn + ni * 16 + l15];

  const int seg = n0 >> 10, nb2 = n0 & 1023;
#pragma unroll
  for (int mi = 0; mi < 4; ++mi) {
#pragma unroll
    for (int reg = 0; reg < 4; ++reg) {
      const int row = m0 + wm + mi * 16 + quad * 4 + reg;
#pragma unroll
      for (int ni = 0; ni < 4; ++ni) {
        float v = acc[mi][ni][reg] + ((MODE == 2 && kz) ? 0.f : bv[ni]);
        if (MODE == 0) {
          Cb[(size_t)row * N + n0 + wn + ni * 16 + l15] = __float2bfloat16(v);
        } else if (MODE == 1) {
          v = fmaxf(v, 0.f);
          Cb[(size_t)row * N + n0 + wn + ni * 16 + l15] = __float2bfloat16(v);
        } else if (MODE == 2) {
          const size_t col = n0 + wn + ni * 16 + l15;
          if (kz == 0) {
            const size_t o = (size_t)row * N + col;
            Cf[o] = v + b2f(*(const short*)&Res[o]);
          } else {
            float* P = (row < 2048) ? Kf : Vf;   // partial bufs (dead ws)
            P[(size_t)(row & 2047) * N + col] = v;
          }
        } else {  // MODE 3
          const size_t o = (size_t)row * 1024 + nb2 + wn + ni * 16 + l15;
          if (seg == 0) {
            Cb[o] = __float2bfloat16(v * 0.125f);   // pre-scale Q by 1/sqrt(hd)
          } else if (seg == 1) {
            Kf[o] = v; Kb[o] = __float2bfloat16(v);
          } else {
            Vf[o] = v; Vb[o] = __float2bfloat16(v);
          }
        }
      }
    }
  }
}

// ---------------------------------------------------------------------------
// MFMA flash attention v5, causal, hd=64.
// Block = (q-tile PAIR {bxp, 31-bxp}, head, batch): every block does exactly
// 33 k-tiles -> perfect inter-CU balance. Grid 512 blocks, 2/CU.
// v5: XCD-LOCALITY REMAP — decode (bxp,h,b) from the linear block id so all
// 16 pair-blocks sharing one (h,b) K/V panel land on the SAME XCD
// (lin&7 = xcd; round-robin dispatch). Each XCD holds 4 groups x 512 KB K/V
// = 2 MB resident in its 4 MB L2 -> K/V fetched from HBM once (was ~2.5x,
// FETCH 122 MB) and the ISSUE prefetch becomes an L2 hit (~200 cy, fully
// hidden under one tile) instead of ~900 cy HBM.
// K and V both reg-staged (global->reg->swizzled ds_write): no vmcnt drain at
// barriers (T4); only counted waits at WRITEKV, one iteration after issue.
// Named score regs (no lambdas/ref-arrays) => no scratch.
// Swizzle: elem col ^= (row&7)<<3 on Ks/Vt/Ps (bank-conflict-free).
// ---------------------------------------------------------------------------
#define BAR_SYNC() do {                                                      \
    asm volatile("s_waitcnt lgkmcnt(0)" ::: "memory");                       \
    __builtin_amdgcn_s_barrier();                                            \
    __builtin_amdgcn_sched_barrier(0);                                       \
  } while (0)

#define ISSUE(KT) do { const size_t ko_ = (size_t)((KT) << 6) * D_;          \
    kr0 = *(const s16x8*)(Kg + ko_);                                         \
    kr1 = *(const s16x8*)(Kg2 + ko_);                                        \
    vr0 = *(const s16x8*)(Vg + ko_);                                         \
    vr1 = *(const s16x8*)(Vg + ko_ + 8);                                     \
  } while (0)

#define WRITEKV(KT) do {                                                     \
    bf16* kd_ = Ks[(KT) & 1];                                                \
    *(s16x8*)&kd_[krow * 64 + (kchunk << 3)] = kr0;                          \
    *(s16x8*)&kd_[(krow + 32) * 64 + (kchunk << 3)] = kr1;                   \
    short* vp_ = (short*)Vt[(KT) & 1];                                       \
    _Pragma("unroll") for (int j = 0; j < 8; ++j) {                          \
      const int d0_ = vd + j, d1_ = vd + 8 + j;                              \
      vp_[d0_ * 64 + (vk ^ ((d0_ & 7) << 3))] = vr0[j];                      \
      vp_[d1_ * 64 + (vk ^ ((d1_ & 7) << 3))] = vr1[j];                      \
    }                                                                        \
  } while (0)

#define QK_LOAD(KT) do { const bf16* Kq_ = Ks[(KT) & 1];                     \
    ka0 = *(const s16x8*)&Kq_[( 0 + l15) * 64 + (( 0 + quad * 8) ^ swr)];    \
    ka1 = *(const s16x8*)&Kq_[(16 + l15) * 64 + (( 0 + quad * 8) ^ swr)];    \
    ka2 = *(const s16x8*)&Kq_[(32 + l15) * 64 + (( 0 + quad * 8) ^ swr)];    \
    ka3 = *(const s16x8*)&Kq_[(48 + l15) * 64 + (( 0 + quad * 8) ^ swr)];    \
    kb0 = *(const s16x8*)&Kq_[( 0 + l15) * 64 + ((32 + quad * 8) ^ swr)];    \
    kb1 = *(const s16x8*)&Kq_[(16 + l15) * 64 + ((32 + quad * 8) ^ swr)];    \
    kb2 = *(const s16x8*)&Kq_[(32 + l15) * 64 + ((32 + quad * 8) ^ swr)];    \
    kb3 = *(const s16x8*)&Kq_[(48 + l15) * 64 + ((32 + quad * 8) ^ swr)];    \
  } while (0)

#define QK_MFMA(S0_, S1_, S2_, S3_) do {                                     \
    f32x4 z_ = {};                                                           \
    z_ = mfma_bf16(qf0, ka0, z_); S0_ = mfma_bf16(qf1, kb0, z_);             \
    z_ = (f32x4){};                                                          \
    z_ = mfma_bf16(qf0, ka1, z_); S1_ = mfma_bf16(qf1, kb1, z_);             \
    z_ = (f32x4){};                                                          \
    z_ = mfma_bf16(qf0, ka2, z_); S2_ = mfma_bf16(qf1, kb2, z_);             \
    z_ = (f32x4){};                                                          \
    z_ = mfma_bf16(qf0, ka3, z_); S3_ = mfma_bf16(qf1, kb3, z_);             \
  } while (0)

#define SMAXPV(J, S0_, S1_, S2_, S3_) do {                                   \
    if ((J) == nt - 1) {  /* diagonal tile only */                           \
      _Pragma("unroll") for (int reg = 0; reg < 4; ++reg) {                  \
        const int qrow_ = qb + (w << 4) + quad * 4 + reg;                    \
        const int k0_ = ((J) << 6) + l15;                                    \
        if (k0_ +  0 > qrow_) S0_[reg] = -1e30f;                             \
        if (k0_ + 16 > qrow_) S1_[reg] = -1e30f;                             \
        if (k0_ + 32 > qrow_) S2_[reg] = -1e30f;                             \
        if (k0_ + 48 > qrow_) S3_[reg] = -1e30f;                             \
      }                                                                      \
    }                                                                        \
    float mx_[4];                                                            \
    _Pragma("unroll") for (int reg = 0; reg < 4; ++reg)                      \
      mx_[reg] = fmaxf(fmaxf(S0_[reg], S1_[reg]), fmaxf(S2_[reg], S3_[reg]));\
    _Pragma("unroll") for (int off = 1; off < 16; off <<= 1)                 \
      _Pragma("unroll") for (int reg = 0; reg < 4; ++reg)                    \
        mx_[reg] = fmaxf(mx_[reg], __shfl_xor(mx_[reg], off, 64));           \
    bool up_ = false;                                                        \
    _Pragma("unroll") for (int reg = 0; reg < 4; ++reg)                      \
      up_ = up_ || (mx_[reg] > m_i[reg] + 8.f);                              \
    if (__any(up_)) {  /* defer-max (T13): rescale only on real growth */    \
      _Pragma("unroll") for (int reg = 0; reg < 4; ++reg) {                  \
        const float nm_ = fmaxf(m_i[reg], mx_[reg]);                         \
        const float al_ = __expf(m_i[reg] - nm_);                            \
        m_i[reg] = nm_; l_p[reg] *= al_;                                     \
        o[0][reg] *= al_; o[1][reg] *= al_;                                  \
        o[2][reg] *= al_; o[3][reg] *= al_;                                  \
      }                                                                      \
    }                                                                        \
    _Pragma("unroll") for (int reg = 0; reg < 4; ++reg) {                    \
      const float e0_ = __expf(S0_[reg] - m_i[reg]);                         \
      const float e1_ = __expf(S1_[reg] - m_i[reg]);                         \
      const float e2_ = __expf(S2_[reg] - m_i[reg]);                         \
      const float e3_ = __expf(S3_[reg] - m_i[reg]);                         \
      l_p[reg] += e0_ + e1_ + e2_ + e3_;                                     \
      const int row_ = quad * 4 + reg;                                       \
      bf16* pr_ = &Ps[w][row_ * 64];                                         \
      const int sx_ = (row_ & 7) << 3;                                       \
      pr_[( 0 + l15) ^ sx_] = __float2bfloat16(e0_);                         \
      pr_[(16 + l15) ^ sx_] = __float2bfloat16(e1_);                         \
      pr_[(32 + l15) ^ sx_] = __float2bfloat16(e2_);                         \
      pr_[(48 + l15) ^ sx_] = __float2bfloat16(e3_);                         \
    }                                                                        \
    {                                                                        \
      const bf16* Vc_ = Vt[(J) & 1];                                         \
      _Pragma("unroll") for (int ks = 0; ks < 2; ++ks) {                     \
        const s16x8 pf_ =                                                    \
            *(const s16x8*)&Ps[w][l15 * 64 + ((ks * 32 + quad * 8) ^ swr)];  \
        _Pragma("unroll") for (int ni = 0; ni < 4; ++ni) {                   \
          const s16x8 vf_ = *(const s16x8*)                                  \
              &Vc_[(ni * 16 + l15) * 64 + ((ks * 32 + quad * 8) ^ swr)];     \
          o[ni] = mfma_bf16(pf_, vf_, o[ni]);                                \
        }                                                                    \
      }                                                                      \
    }                                                                        \
  } while (0)

#define BODY(KT, SO0, SO1, SO2, SO3, SN0, SN1, SN2, SN3) do {                \
    WRITEKV(KT);                                                             \
    BAR_SYNC();                                                              \
    if ((KT) + 1 < nt) ISSUE((KT) + 1);                                      \
    QK_LOAD(KT);                                                             \
    QK_MFMA(SN0, SN1, SN2, SN3);                                             \
    SMAXPV((KT) - 1, SO0, SO1, SO2, SO3);                                    \
    BAR_SYNC();                                                              \
  } while (0)

__global__ __launch_bounds__(256, 2) void flash_attn(
    const bf16* __restrict__ Q, const bf16* __restrict__ Kk,
    const bf16* __restrict__ V, bf16* __restrict__ O) {
  // XCD-locality decode: all 16 pair-blocks of one (h,b) -> same XCD.
  const int lin = (int)(blockIdx.x + 16 * blockIdx.y + 256 * blockIdx.z);
  const int xcd = lin & 7;
  const int slot = lin >> 3;                  // 0..63
  const int bxp = slot >> 2;                  // 0..15: q-tile pair id
  const int g = xcd + ((slot & 3) << 3);      // 0..31: (h,b) group
  const int h = g & 15, b = g >> 4;

  const int t = threadIdx.x, w = t >> 6, l = t & 63;
  const int l15 = l & 15, quad = l >> 4;
  __shared__ __align__(16) bf16 Ks[2][64 * 64];    // [buf][key][d] swizzled
  __shared__ __align__(16) bf16 Vt[2][64 * 64];    // [buf][d][key] swizzled
  __shared__ __align__(16) bf16 Ps[4][16 * 64];    // per-wave P, swizzled

  // K staging: linear global chunk; swizzle applied at ds_write dest.
  const int krow = t >> 3;                    // 0..31
  const int kchunk = (t & 7) ^ (krow & 7);    // swizzled LDS chunk
  const bf16* Kg  = Kk + (size_t)(b * S_ + krow) * D_ + h * HD_ + ((t & 7) << 3);
  const bf16* Kg2 = Kg + (size_t)32 * D_;
  const int vk = t & 63, vd = w << 4;
  const bf16* Vg = V + (size_t)(b * S_ + vk) * D_ + h * HD_ + vd;
  const int swr = (l15 & 7) << 3;             // read-side xor (elements)

  s16x8 kr0, kr1, vr0, vr1;                   // staging regs (1 tile)
  s16x8 ka0, ka1, ka2, ka3, kb0, kb1, kb2, kb3;  // K fragment regs

#pragma unroll 1
  for (int ph = 0; ph < 2; ++ph) {
    const int qt = ph ? (S_ / 64 - 1 - bxp) : bxp;
    const int qb = qt << 6;
    const int nt = qt + 1;

    __syncthreads();   // protect LDS reuse across phases (full drain, 2x total)

    const bf16* qp =
        Q + (size_t)(b * S_ + qb + (w << 4) + l15) * D_ + h * HD_ + quad * 8;
    const s16x8 qf0 = *(const s16x8*)qp;
    const s16x8 qf1 = *(const s16x8*)(qp + 32);

    f32x4 o[4] = {};
    float m_i[4], l_p[4];
#pragma unroll
    for (int r = 0; r < 4; ++r) { m_i[r] = -1e30f; l_p[r] = 0.f; }

    f32x4 sA0, sA1, sA2, sA3, sB0, sB1, sB2, sB3;

    // ---- prologue: tile 0 ----
    ISSUE(0);
    WRITEKV(0);                  // counted vmcnt waits for kr/vr (cold, once)
    BAR_SYNC();
    if (nt > 1) ISSUE(1);
    QK_LOAD(0);
    QK_MFMA(sA0, sA1, sA2, sA3);
    BAR_SYNC();

    // ---- main loop: 2-stage score pipeline, hand-unrolled ping-pong ----
    int kt = 1;
    for (; kt + 1 < nt; kt += 2) {
      BODY(kt,     sA0, sA1, sA2, sA3, sB0, sB1, sB2, sB3);
      BODY(kt + 1, sB0, sB1, sB2, sB3, sA0, sA1, sA2, sA3);
    }
    if (kt < nt) {
      BODY(kt, sA0, sA1, sA2, sA3, sB0, sB1, sB2, sB3);
      SMAXPV(nt - 1, sB0, sB1, sB2, sB3);
    } else {
      SMAXPV(nt - 1, sA0, sA1, sA2, sA3);
    }

    // ---- epilogue: deferred l reduction + O write ----
    float inv[4];
#pragma unroll
    for (int off = 1; off < 16; off <<= 1)
#pragma unroll
      for (int reg = 0; reg < 4; ++reg)
        l_p[reg] += __shfl_xor(l_p[reg], off, 64);
#pragma unroll
    for (int reg = 0; reg < 4; ++reg) inv[reg] = 1.f / l_p[reg];

#pragma unroll
    for (int reg = 0; reg < 4; ++reg) {
      const int row = b * S_ + qb + (w << 4) + quad * 4 + reg;
      bf16* op = O + (size_t)row * D_ + h * HD_ + l15;
#pragma unroll
      for (int ni = 0; ni < 4; ++ni)
        op[ni * 16] = __float2bfloat16(o[ni][reg] * inv[reg]);
    }
  }
}

// ---------------------------------------------------------------------------
// LN1 (MODE 0): h1 = LN(x_f32 + y1_bf16) -> bf16.
// LN2 (MODE 1): out = LN(X + PA/PB partial) -> fp32 in place (X=out holds
//               K-half-0 + bias + resid; PA/PB hold K-half-1 partial).
// One block per 1024-col row.
// ---------------------------------------------------------------------------
template <int MODE>   // 0: LN1, 1: LN2
__global__ __launch_bounds__(256) void add_ln(
    const float* __restrict__ X, const bf16* __restrict__ Y,
    const float* __restrict__ PA, const float* __restrict__ PB,
    const float* __restrict__ g, const float* __restrict__ be,
    void* Out) {
  const int row = blockIdx.x, t = threadIdx.x;
  const size_t base = (size_t)row * D_ + t * 4;
  const float* P = (MODE == 1)
      ? ((row < 2048) ? PA + base : PB + (base - (size_t)2048 * D_))
      : nullptr;
  float v[4];
  float s = 0.f, q = 0.f;
#pragma unroll
  for (int i = 0; i < 4; ++i) {
    v[i] = X[base + i];
    if (MODE == 0) v[i] += b2f(*(const short*)&Y[base + i]);
    else           v[i] += P[i];
    s += v[i];
    q += v[i] * v[i];
  }
#pragma unroll
  for (int off = 32; off; off >>= 1) {
    s += __shfl_down(s, off, 64);
    q += __shfl_down(q, off, 64);
  }
  __shared__ float rs[4], rq[4];
  const int w = t >> 6, l = t & 63;
  if (l == 0) { rs[w] = s; rq[w] = q; }
  __syncthreads();
  s = rs[0] + rs[1] + rs[2] + rs[3];
  q = rq[0] + rq[1] + rq[2] + rq[3];
  const float mu = s * (1.f / D_);
  const float var = q * (1.f / D_) - mu * mu;
  const float rstd = rsqrtf(var + 1e-5f);
#pragma unroll
  for (int i = 0; i < 4; ++i) {
    const float r = (v[i] - mu) * rstd * g[t * 4 + i] + be[t * 4 + i];
    if (MODE == 0) ((bf16*)Out)[base + i] = __float2bfloat16(r);
    else           ((float*)Out)[base + i] = r;
  }
}

extern "C" void kernel_launch(void* const* d_in, const int* in_sizes, int n_in,
                              void* d_out, int out_size, void* d_ws, size_t ws_size,
                              hipStream_t stream) {
  const float* x     = (const float*)d_in[0];
  const float* qkv_b = (const float*)d_in[2];
  const float* out_b = (const float*)d_in[4];
  const float* b1    = (const float*)d_in[6];
  const float* b2    = (const float*)d_in[8];
  const float* l1w   = (const float*)d_in[9];
  const float* l1b   = (const float*)d_in[10];
  const float* l2w   = (const float*)d_in[11];
  const float* l2b   = (const float*)d_in[12];

  float* out    = (float*)d_out;
  float* kcache = out + (size_t)M_ * D_;
  float* vcache = kcache + (size_t)M_ * D_;

  // ws (bf16 elems). High-water 36M elems = 72 MB (<75 MB established safe).
  //  [0,4M)   xc      -> attnb (after QKV) -> pA fp32 partial (after outproj)
  //  [4,7M)   wqkv    -> h1 (after out-proj; h1 spans [4,8M))
  //  [7,8M)   wout
  //  [8,12M)  w1c
  //  [12,16M) w2c
  //  [16,20M) qbuf    -> y1 (after flash) -> pB fp32 partial (after ln1)
  //  [20,24M) kb      -> ffb (after flash; full ffb spans [20,36M))
  //  [24,28M) vb
  bf16* ws    = (bf16*)d_ws;
  bf16* xc    = ws;
  bf16* attnb = ws;
  bf16* wqkv  = ws + 4 * MEG;
  bf16* h1    = ws + 4 * MEG;
  bf16* wout  = ws + 7 * MEG;
  bf16* w1c   = ws + 8 * MEG;
  bf16* w2c   = ws + 12 * MEG;
  bf16* qbuf  = ws + 16 * MEG;
  bf16* y1    = ws + 16 * MEG;
  bf16* kb    = ws + 20 * MEG;
  bf16* ffb   = ws + 20 * MEG;
  bf16* vb    = ws + 24 * MEG;
  float* pA   = (float*)ws;               // rows 0..2047  K-half-1 partial
  float* pB   = (float*)(ws + 16 * MEG);  // rows 2048..4095

  const dim3 blk(256);

  // all 5 fp32->bf16 conversions in one dispatch
  CvtArgs ca;
  ca.src[0] = x;                    ca.dst[0] = xc;   ca.n[0] = M_ * D_;
  ca.src[1] = (const float*)d_in[1]; ca.dst[1] = wqkv; ca.n[1] = 3 * D_ * D_;
  ca.src[2] = (const float*)d_in[3]; ca.dst[2] = wout; ca.n[2] = D_ * D_;
  ca.src[3] = (const float*)d_in[5]; ca.dst[3] = w1c;  ca.n[3] = FFD_ * D_;
  ca.src[4] = (const float*)d_in[7]; ca.dst[4] = w2c;  ca.n[4] = D_ * FFD_;
  cvt_f2b_multi<<<dim3((M_ * D_ + 2047) / 2048, 5), blk, 0, stream>>>(ca);

  // QKV: q (pre-scaled 0.125) -> qbuf bf16; k/v->fp32 caches + bf16 ws copies.
  gemm_bt<3><<<dim3(3 * D_ / 128, M_ / 128), blk, 0, stream>>>(
      xc, wqkv, qkv_b, qbuf, nullptr, kcache, kb, vcache, vb, nullptr,
      M_, 3 * D_, D_);
  flash_attn<<<dim3(S_ / 128, H_, B_), blk, 0, stream>>>(qbuf, kb, vb, attnb);
  // out-proj -> y1 bf16 (overwrites dead qbuf)
  gemm_bt<0><<<dim3(D_ / 128, M_ / 128), blk, 0, stream>>>(
      attnb, wout, out_b, y1, nullptr, nullptr, nullptr, nullptr, nullptr,
      nullptr, M_, D_, D_);
  // h1 = LN(x + y1) -> bf16 (overwrites dead wqkv)
  add_ln<0><<<dim3(M_), blk, 0, stream>>>(x, y1, nullptr, nullptr, l1w, l1b, h1);
  // MLP full-M: MLP1 -> ffb [20,36M); MLP2 split-K=2:
  // z=0 K-half-0 + bias + resid -> out; z=1 K-half-1 raw -> pA/pB.
  gemm_bt<1><<<dim3(FFD_ / 128, M_ / 128), blk, 0, stream>>>(
      h1, w1c, b1, ffb, nullptr, nullptr, nullptr, nullptr, nullptr,
      nullptr, M_, FFD_, D_);
  gemm_bt<2><<<dim3(D_ / 128, M_ / 128, 2), blk, 0, stream>>>(
      ffb, w2c, b2, nullptr, out, pA, nullptr, pB, nullptr,
      h1, M_, D_, FFD_);
  // out = LN(out + partial) in place, fp32.
  add_ln<1><<<dim3(M_), blk, 0, stream>>>(out, nullptr, pA, pB, l2w, l2b, out);
}

// Round 8
// 372.062 us; speedup vs baseline: 1.0490x; 1.0490x over previous
//
#include <hip/hip_runtime.h>
#include <hip/hip_bf16.h>
#include <stdint.h>

typedef __hip_bfloat16 bf16;
typedef __attribute__((ext_vector_type(8))) short s16x8;
typedef __attribute__((ext_vector_type(4))) float f32x4;

#define B_   2
#define S_   2048
#define D_   1024
#define H_   16
#define HD_  64
#define FFD_ 4096
#define M_   4096
#define MEG  ((size_t)1048576)

__device__ __forceinline__ f32x4 mfma_bf16(s16x8 a, s16x8 b, f32x4 c) {
  return __builtin_amdgcn_mfma_f32_16x16x32_bf16(a, b, c, 0, 0, 0);
}

__device__ __forceinline__ void gl_lds16(const bf16* g, bf16* l) {
  __builtin_amdgcn_global_load_lds(
      (const __attribute__((address_space(1))) void*)g,
      (__attribute__((address_space(3))) void*)l, 16, 0, 0);
}

__device__ __forceinline__ float b2f(short u) {
  union { uint32_t i; float f; } z;
  z.i = ((uint32_t)(unsigned short)u) << 16;
  return z.f;
}
__device__ __forceinline__ short f2b(float f) {
  const bf16 h = __float2bfloat16(f);
  return *(const short*)&h;
}

// ---------------------------------------------------------------------------
// fp32 -> bf16 conversion, all 5 tensors in ONE dispatch (z-indexed).
// ---------------------------------------------------------------------------
struct CvtArgs {
  const float* src[5];
  bf16* dst[5];
  int n[5];
};
__global__ __launch_bounds__(256) void cvt_f2b_multi(CvtArgs a) {
  const int z = blockIdx.y;
  const int idx = (blockIdx.x * 256 + threadIdx.x) * 8;
  if (idx >= a.n[z]) return;
  const float* src = a.src[z];
  s16x8 o;
#pragma unroll
  for (int i = 0; i < 8; ++i) o[i] = f2b(src[idx + i]);
  *(s16x8*)(a.dst[z] + idx) = o;
}

// ---------------------------------------------------------------------------
// MFMA NT GEMM: C[m,n] = sum_k A[m,k]*W[n,k] + bias[n]  (bias fp32)
// 128x128 tile, 4 waves (2x2), 4x4 16x16x32 frags.
// v4: REVERT to round-5 v2 loop (2-buffer gl_lds, one __syncthreads drain
//     per K-step — 67 us verified on MLP2; the round-6 counted-vmcnt 3-buffer
//     pipeline measured 77 us, post-mortem: compiler re-drains vmcnt anyway).
//     MODE 2 only: BK=64 (grid is 2 blocks/CU so 64 KB LDS costs no
//     occupancy; halves the number of barrier-drain events 64->32).
//     BK=64 needs chunk-XOR swizzle (128 B row stride = full bank wrap):
//     LDS phys chunk c at row r holds global chunk c^(r&7); read side
//     applies ^(l15&7). Arithmetic order bit-identical to BK=32.
//     T1 XCD-chunked block swizzle kept (FETCH 139->53 MB, round 5).
// MODE 0: C -> bf16 Cb             (out-proj -> y1)
// MODE 1: relu, C -> bf16 Cb       (MLP1 -> ff)
// MODE 2: SPLIT-K=2 (gridDim.z=2). z=0: K-half-0 + bias + resid -> fp32 Cf.
//         z=1: K-half-1 raw partial -> fp32 Kf (rows<2048) / Vf (rows>=2048).
// MODE 3: QKV split: seg0 q*0.125 -> bf16 Cb (pre-scaled for attn);
//         seg1 k->fp32 Kf + bf16 Kb; seg2 v->fp32 Vf + bf16 Vb.
// ---------------------------------------------------------------------------
template <int MODE>
__global__ __launch_bounds__(256) void gemm_bt(
    const bf16* __restrict__ A, const bf16* __restrict__ W,
    const float* __restrict__ bias,
    bf16* __restrict__ Cb, float* __restrict__ Cf,
    float* __restrict__ Kf, bf16* __restrict__ Kb,
    float* __restrict__ Vf, bf16* __restrict__ Vb,
    const bf16* __restrict__ Res,
    int M, int N, int K) {
  constexpr int BK = (MODE == 2) ? 64 : 32;
  __shared__ __align__(16) bf16 As[2][128 * BK];
  __shared__ __align__(16) bf16 Bs[2][128 * BK];
  const int t = threadIdx.x;

  // T1 XCD-chunked swizzle (all grids have nwg % 8 == 0 -> bijective).
  const int nwg = gridDim.x * gridDim.y;
  const int bid = blockIdx.y * gridDim.x + blockIdx.x;
  const int sw  = (bid & 7) * (nwg >> 3) + (bid >> 3);
  const int m0 = (sw / gridDim.x) << 7, n0 = (sw % gridDim.x) << 7;

  const int w = t >> 6, l = t & 63;
  const int wm = (w >> 1) << 6, wn = (w & 1) << 6;
  const int l15 = l & 15, quad = l >> 4;

  const int kz   = (MODE == 2) ? (int)blockIdx.z : 0;   // K-split index
  const int Keff = (MODE == 2) ? (K >> 1) : K;

  f32x4 acc[4][4] = {};

  // staging addresses
  const int srow = (BK == 32) ? (t >> 2) : (t >> 3);
  const int scol = (BK == 32) ? ((t & 3) << 3)
                              : (((t & 7) ^ ((t >> 3) & 7)) << 3);  // pre-swz
  const bf16* Ag  = A + (size_t)(m0 + srow) * K + kz * Keff + scol;
  const bf16* Ag2 = Ag + ((size_t)K << 6);   // +64 rows (BK=32 path)
  const bf16* Wg  = W + (size_t)(n0 + srow) * K + kz * Keff + scol;
  const bf16* Wg2 = Wg + ((size_t)K << 6);

#define STAGE_G(KI, BUF) do {                                                \
    if constexpr (BK == 32) {                                                \
      const int ko_ = (KI) * 32;                                             \
      gl_lds16(Ag + ko_, (bf16*)As[BUF] + t * 8);                            \
      gl_lds16(Ag2 + ko_, (bf16*)As[BUF] + 2048 + t * 8);                    \
      gl_lds16(Wg + ko_, (bf16*)Bs[BUF] + t * 8);                            \
      gl_lds16(Wg2 + ko_, (bf16*)Bs[BUF] + 2048 + t * 8);                    \
    } else {                                                                 \
      const int ko_ = (KI) * 64;                                             \
      _Pragma("unroll") for (int i_ = 0; i_ < 4; ++i_) {                     \
        gl_lds16(Ag + ko_ + (size_t)32 * K * i_,                             \
                 (bf16*)As[BUF] + i_ * 2048 + t * 8);                        \
        gl_lds16(Wg + ko_ + (size_t)32 * K * i_,                             \
                 (bf16*)Bs[BUF] + i_ * 2048 + t * 8);                        \
      }                                                                      \
    }                                                                        \
  } while (0)

  const int nk = Keff / BK;
  STAGE_G(0, 0);
  __syncthreads();

  for (int ki = 0; ki < nk; ++ki) {
    const int cur = ki & 1;
    if (ki + 1 < nk) STAGE_G(ki + 1, cur ^ 1);

    const s16x8* As8 = (const s16x8*)As[cur];
    const s16x8* Bs8 = (const s16x8*)Bs[cur];
    if constexpr (BK == 32) {
      s16x8 af[4], bfr[4];
#pragma unroll
      for (int i = 0; i < 4; ++i) af[i]  = As8[((wm + i * 16 + l15) << 2) + quad];
#pragma unroll
      for (int i = 0; i < 4; ++i) bfr[i] = Bs8[((wn + i * 16 + l15) << 2) + quad];
#pragma unroll
      for (int mi = 0; mi < 4; ++mi)
#pragma unroll
        for (int ni = 0; ni < 4; ++ni)
          acc[mi][ni] = mfma_bf16(af[mi], bfr[ni], acc[mi][ni]);
    } else {
      const int sx = l15 & 7;
#pragma unroll
      for (int h = 0; h < 2; ++h) {
        s16x8 af[4], bfr[4];
#pragma unroll
        for (int i = 0; i < 4; ++i)
          af[i]  = As8[((wm + i * 16 + l15) << 3) + ((h * 4 + quad) ^ sx)];
#pragma unroll
        for (int i = 0; i < 4; ++i)
          bfr[i] = Bs8[((wn + i * 16 + l15) << 3) + ((h * 4 + quad) ^ sx)];
#pragma unroll
        for (int mi = 0; mi < 4; ++mi)
#pragma unroll
          for (int ni = 0; ni < 4; ++ni)
            acc[mi][ni] = mfma_bf16(af[mi], bfr[ni], acc[mi][ni]);
      }
    }
    __syncthreads();
  }
#undef STAGE_G

  float bv[4];
#pragma unroll
  for (int ni = 0; ni < 4; ++ni)
    bv[ni] = bias[n0 + wn + ni * 16 + l15];

  const int seg = n0 >> 10, nb2 = n0 & 1023;
#pragma unroll
  for (int mi = 0; mi < 4; ++mi) {
#pragma unroll
    for (int reg = 0; reg < 4; ++reg) {
      const int row = m0 + wm + mi * 16 + quad * 4 + reg;
#pragma unroll
      for (int ni = 0; ni < 4; ++ni) {
        float v = acc[mi][ni][reg] + ((MODE == 2 && kz) ? 0.f : bv[ni]);
        if (MODE == 0) {
          Cb[(size_t)row * N + n0 + wn + ni * 16 + l15] = __float2bfloat16(v);
        } else if (MODE == 1) {
          v = fmaxf(v, 0.f);
          Cb[(size_t)row * N + n0 + wn + ni * 16 + l15] = __float2bfloat16(v);
        } else if (MODE == 2) {
          const size_t col = n0 + wn + ni * 16 + l15;
          if (kz == 0) {
            const size_t o = (size_t)row * N + col;
            Cf[o] = v + b2f(*(const short*)&Res[o]);
          } else {
            float* P = (row < 2048) ? Kf : Vf;   // partial bufs (dead ws)
            P[(size_t)(row & 2047) * N + col] = v;
          }
        } else {  // MODE 3
          const size_t o = (size_t)row * 1024 + nb2 + wn + ni * 16 + l15;
          if (seg == 0) {
            Cb[o] = __float2bfloat16(v * 0.125f);   // pre-scale Q by 1/sqrt(hd)
          } else if (seg == 1) {
            Kf[o] = v; Kb[o] = __float2bfloat16(v);
          } else {
            Vf[o] = v; Vb[o] = __float2bfloat16(v);
          }
        }
      }
    }
  }
}

// ---------------------------------------------------------------------------
// MFMA flash attention v5, causal, hd=64.  (unchanged from round 7)
// Block = (q-tile PAIR {bxp, 31-bxp}, head, batch): every block does exactly
// 33 k-tiles -> perfect inter-CU balance. Grid 512 blocks, 2/CU.
// XCD-locality decode: all 16 pair-blocks of one (h,b) land on the same XCD.
// K and V both reg-staged (global->reg->swizzled ds_write): no vmcnt drain at
// barriers (T4); only counted waits at WRITEKV, one iteration after issue.
// Named score regs (no lambdas/ref-arrays) => no scratch.
// Swizzle: elem col ^= (row&7)<<3 on Ks/Vt/Ps (bank-conflict-free).
// ---------------------------------------------------------------------------
#define BAR_SYNC() do {                                                      \
    asm volatile("s_waitcnt lgkmcnt(0)" ::: "memory");                       \
    __builtin_amdgcn_s_barrier();                                            \
    __builtin_amdgcn_sched_barrier(0);                                       \
  } while (0)

#define ISSUE(KT) do { const size_t ko_ = (size_t)((KT) << 6) * D_;          \
    kr0 = *(const s16x8*)(Kg + ko_);                                         \
    kr1 = *(const s16x8*)(Kg2 + ko_);                                        \
    vr0 = *(const s16x8*)(Vg + ko_);                                         \
    vr1 = *(const s16x8*)(Vg + ko_ + 8);                                     \
  } while (0)

#define WRITEKV(KT) do {                                                     \
    bf16* kd_ = Ks[(KT) & 1];                                                \
    *(s16x8*)&kd_[krow * 64 + (kchunk << 3)] = kr0;                          \
    *(s16x8*)&kd_[(krow + 32) * 64 + (kchunk << 3)] = kr1;                   \
    short* vp_ = (short*)Vt[(KT) & 1];                                       \
    _Pragma("unroll") for (int j = 0; j < 8; ++j) {                          \
      const int d0_ = vd + j, d1_ = vd + 8 + j;                              \
      vp_[d0_ * 64 + (vk ^ ((d0_ & 7) << 3))] = vr0[j];                      \
      vp_[d1_ * 64 + (vk ^ ((d1_ & 7) << 3))] = vr1[j];                      \
    }                                                                        \
  } while (0)

#define QK_LOAD(KT) do { const bf16* Kq_ = Ks[(KT) & 1];                     \
    ka0 = *(const s16x8*)&Kq_[( 0 + l15) * 64 + (( 0 + quad * 8) ^ swr)];    \
    ka1 = *(const s16x8*)&Kq_[(16 + l15) * 64 + (( 0 + quad * 8) ^ swr)];    \
    ka2 = *(const s16x8*)&Kq_[(32 + l15) * 64 + (( 0 + quad * 8) ^ swr)];    \
    ka3 = *(const s16x8*)&Kq_[(48 + l15) * 64 + (( 0 + quad * 8) ^ swr)];    \
    kb0 = *(const s16x8*)&Kq_[( 0 + l15) * 64 + ((32 + quad * 8) ^ swr)];    \
    kb1 = *(const s16x8*)&Kq_[(16 + l15) * 64 + ((32 + quad * 8) ^ swr)];    \
    kb2 = *(const s16x8*)&Kq_[(32 + l15) * 64 + ((32 + quad * 8) ^ swr)];    \
    kb3 = *(const s16x8*)&Kq_[(48 + l15) * 64 + ((32 + quad * 8) ^ swr)];    \
  } while (0)

#define QK_MFMA(S0_, S1_, S2_, S3_) do {                                     \
    f32x4 z_ = {};                                                           \
    z_ = mfma_bf16(qf0, ka0, z_); S0_ = mfma_bf16(qf1, kb0, z_);             \
    z_ = (f32x4){};                                                          \
    z_ = mfma_bf16(qf0, ka1, z_); S1_ = mfma_bf16(qf1, kb1, z_);             \
    z_ = (f32x4){};                                                          \
    z_ = mfma_bf16(qf0, ka2, z_); S2_ = mfma_bf16(qf1, kb2, z_);             \
    z_ = (f32x4){};                                                          \
    z_ = mfma_bf16(qf0, ka3, z_); S3_ = mfma_bf16(qf1, kb3, z_);             \
  } while (0)

#define SMAXPV(J, S0_, S1_, S2_, S3_) do {                                   \
    if ((J) == nt - 1) {  /* diagonal tile only */                           \
      _Pragma("unroll") for (int reg = 0; reg < 4; ++reg) {                  \
        const int qrow_ = qb + (w << 4) + quad * 4 + reg;                    \
        const int k0_ = ((J) << 6) + l15;                                    \
        if (k0_ +  0 > qrow_) S0_[reg] = -1e30f;                             \
        if (k0_ + 16 > qrow_) S1_[reg] = -1e30f;                             \
        if (k0_ + 32 > qrow_) S2_[reg] = -1e30f;                             \
        if (k0_ + 48 > qrow_) S3_[reg] = -1e30f;                             \
      }                                                                      \
    }                                                                        \
    float mx_[4];                                                            \
    _Pragma("unroll") for (int reg = 0; reg < 4; ++reg)                      \
      mx_[reg] = fmaxf(fmaxf(S0_[reg], S1_[reg]), fmaxf(S2_[reg], S3_[reg]));\
    _Pragma("unroll") for (int off = 1; off < 16; off <<= 1)                 \
      _Pragma("unroll") for (int reg = 0; reg < 4; ++reg)                    \
        mx_[reg] = fmaxf(mx_[reg], __shfl_xor(mx_[reg], off, 64));           \
    bool up_ = false;                                                        \
    _Pragma("unroll") for (int reg = 0; reg < 4; ++reg)                      \
      up_ = up_ || (mx_[reg] > m_i[reg] + 8.f);                              \
    if (__any(up_)) {  /* defer-max (T13): rescale only on real growth */    \
      _Pragma("unroll") for (int reg = 0; reg < 4; ++reg) {                  \
        const float nm_ = fmaxf(m_i[reg], mx_[reg]);                         \
        const float al_ = __expf(m_i[reg] - nm_);                            \
        m_i[reg] = nm_; l_p[reg] *= al_;                                     \
        o[0][reg] *= al_; o[1][reg] *= al_;                                  \
        o[2][reg] *= al_; o[3][reg] *= al_;                                  \
      }                                                                      \
    }                                                                        \
    _Pragma("unroll") for (int reg = 0; reg < 4; ++reg) {                    \
      const float e0_ = __expf(S0_[reg] - m_i[reg]);                         \
      const float e1_ = __expf(S1_[reg] - m_i[reg]);                         \
      const float e2_ = __expf(S2_[reg] - m_i[reg]);                         \
      const float e3_ = __expf(S3_[reg] - m_i[reg]);                         \
      l_p[reg] += e0_ + e1_ + e2_ + e3_;                                     \
      const int row_ = quad * 4 + reg;                                       \
      bf16* pr_ = &Ps[w][row_ * 64];                                         \
      const int sx_ = (row_ & 7) << 3;                                       \
      pr_[( 0 + l15) ^ sx_] = __float2bfloat16(e0_);                         \
      pr_[(16 + l15) ^ sx_] = __float2bfloat16(e1_);                         \
      pr_[(32 + l15) ^ sx_] = __float2bfloat16(e2_);                         \
      pr_[(48 + l15) ^ sx_] = __float2bfloat16(e3_);                         \
    }                                                                        \
    {                                                                        \
      const bf16* Vc_ = Vt[(J) & 1];                                         \
      _Pragma("unroll") for (int ks = 0; ks < 2; ++ks) {                     \
        const s16x8 pf_ =                                                    \
            *(const s16x8*)&Ps[w][l15 * 64 + ((ks * 32 + quad * 8) ^ swr)];  \
        _Pragma("unroll") for (int ni = 0; ni < 4; ++ni) {                   \
          const s16x8 vf_ = *(const s16x8*)                                  \
              &Vc_[(ni * 16 + l15) * 64 + ((ks * 32 + quad * 8) ^ swr)];     \
          o[ni] = mfma_bf16(pf_, vf_, o[ni]);                                \
        }                                                                    \
      }                                                                      \
    }                                                                        \
  } while (0)

#define BODY(KT, SO0, SO1, SO2, SO3, SN0, SN1, SN2, SN3) do {                \
    WRITEKV(KT);                                                             \
    BAR_SYNC();                                                              \
    if ((KT) + 1 < nt) ISSUE((KT) + 1);                                      \
    QK_LOAD(KT);                                                             \
    QK_MFMA(SN0, SN1, SN2, SN3);                                             \
    SMAXPV((KT) - 1, SO0, SO1, SO2, SO3);                                    \
    BAR_SYNC();                                                              \
  } while (0)

__global__ __launch_bounds__(256, 2) void flash_attn(
    const bf16* __restrict__ Q, const bf16* __restrict__ Kk,
    const bf16* __restrict__ V, bf16* __restrict__ O) {
  // XCD-locality decode: all 16 pair-blocks of one (h,b) -> same XCD.
  const int lin = (int)(blockIdx.x + 16 * blockIdx.y + 256 * blockIdx.z);
  const int xcd = lin & 7;
  const int slot = lin >> 3;                  // 0..63
  const int bxp = slot >> 2;                  // 0..15: q-tile pair id
  const int g = xcd + ((slot & 3) << 3);      // 0..31: (h,b) group
  const int h = g & 15, b = g >> 4;

  const int t = threadIdx.x, w = t >> 6, l = t & 63;
  const int l15 = l & 15, quad = l >> 4;
  __shared__ __align__(16) bf16 Ks[2][64 * 64];    // [buf][key][d] swizzled
  __shared__ __align__(16) bf16 Vt[2][64 * 64];    // [buf][d][key] swizzled
  __shared__ __align__(16) bf16 Ps[4][16 * 64];    // per-wave P, swizzled

  // K staging: linear global chunk; swizzle applied at ds_write dest.
  const int krow = t >> 3;                    // 0..31
  const int kchunk = (t & 7) ^ (krow & 7);    // swizzled LDS chunk
  const bf16* Kg  = Kk + (size_t)(b * S_ + krow) * D_ + h * HD_ + ((t & 7) << 3);
  const bf16* Kg2 = Kg + (size_t)32 * D_;
  const int vk = t & 63, vd = w << 4;
  const bf16* Vg = V + (size_t)(b * S_ + vk) * D_ + h * HD_ + vd;
  const int swr = (l15 & 7) << 3;             // read-side xor (elements)

  s16x8 kr0, kr1, vr0, vr1;                   // staging regs (1 tile)
  s16x8 ka0, ka1, ka2, ka3, kb0, kb1, kb2, kb3;  // K fragment regs

#pragma unroll 1
  for (int ph = 0; ph < 2; ++ph) {
    const int qt = ph ? (S_ / 64 - 1 - bxp) : bxp;
    const int qb = qt << 6;
    const int nt = qt + 1;

    __syncthreads();   // protect LDS reuse across phases (full drain, 2x total)

    const bf16* qp =
        Q + (size_t)(b * S_ + qb + (w << 4) + l15) * D_ + h * HD_ + quad * 8;
    const s16x8 qf0 = *(const s16x8*)qp;
    const s16x8 qf1 = *(const s16x8*)(qp + 32);

    f32x4 o[4] = {};
    float m_i[4], l_p[4];
#pragma unroll
    for (int r = 0; r < 4; ++r) { m_i[r] = -1e30f; l_p[r] = 0.f; }

    f32x4 sA0, sA1, sA2, sA3, sB0, sB1, sB2, sB3;

    // ---- prologue: tile 0 ----
    ISSUE(0);
    WRITEKV(0);                  // counted vmcnt waits for kr/vr (cold, once)
    BAR_SYNC();
    if (nt > 1) ISSUE(1);
    QK_LOAD(0);
    QK_MFMA(sA0, sA1, sA2, sA3);
    BAR_SYNC();

    // ---- main loop: 2-stage score pipeline, hand-unrolled ping-pong ----
    int kt = 1;
    for (; kt + 1 < nt; kt += 2) {
      BODY(kt,     sA0, sA1, sA2, sA3, sB0, sB1, sB2, sB3);
      BODY(kt + 1, sB0, sB1, sB2, sB3, sA0, sA1, sA2, sA3);
    }
    if (kt < nt) {
      BODY(kt, sA0, sA1, sA2, sA3, sB0, sB1, sB2, sB3);
      SMAXPV(nt - 1, sB0, sB1, sB2, sB3);
    } else {
      SMAXPV(nt - 1, sA0, sA1, sA2, sA3);
    }

    // ---- epilogue: deferred l reduction + O write ----
    float inv[4];
#pragma unroll
    for (int off = 1; off < 16; off <<= 1)
#pragma unroll
      for (int reg = 0; reg < 4; ++reg)
        l_p[reg] += __shfl_xor(l_p[reg], off, 64);
#pragma unroll
    for (int reg = 0; reg < 4; ++reg) inv[reg] = 1.f / l_p[reg];

#pragma unroll
    for (int reg = 0; reg < 4; ++reg) {
      const int row = b * S_ + qb + (w << 4) + quad * 4 + reg;
      bf16* op = O + (size_t)row * D_ + h * HD_ + l15;
#pragma unroll
      for (int ni = 0; ni < 4; ++ni)
        op[ni * 16] = __float2bfloat16(o[ni][reg] * inv[reg]);
    }
  }
}

// ---------------------------------------------------------------------------
// LN1 (MODE 0): h1 = LN(x_f32 + y1_bf16) -> bf16.
// LN2 (MODE 1): out = LN(X + PA/PB partial) -> fp32 in place (X=out holds
//               K-half-0 + bias + resid; PA/PB hold K-half-1 partial).
// One block per 1024-col row.
// ---------------------------------------------------------------------------
template <int MODE>   // 0: LN1, 1: LN2
__global__ __launch_bounds__(256) void add_ln(
    const float* __restrict__ X, const bf16* __restrict__ Y,
    const float* __restrict__ PA, const float* __restrict__ PB,
    const float* __restrict__ g, const float* __restrict__ be,
    void* Out) {
  const int row = blockIdx.x, t = threadIdx.x;
  const size_t base = (size_t)row * D_ + t * 4;
  const float* P = (MODE == 1)
      ? ((row < 2048) ? PA + base : PB + (base - (size_t)2048 * D_))
      : nullptr;
  float v[4];
  float s = 0.f, q = 0.f;
#pragma unroll
  for (int i = 0; i < 4; ++i) {
    v[i] = X[base + i];
    if (MODE == 0) v[i] += b2f(*(const short*)&Y[base + i]);
    else           v[i] += P[i];
    s += v[i];
    q += v[i] * v[i];
  }
#pragma unroll
  for (int off = 32; off; off >>= 1) {
    s += __shfl_down(s, off, 64);
    q += __shfl_down(q, off, 64);
  }
  __shared__ float rs[4], rq[4];
  const int w = t >> 6, l = t & 63;
  if (l == 0) { rs[w] = s; rq[w] = q; }
  __syncthreads();
  s = rs[0] + rs[1] + rs[2] + rs[3];
  q = rq[0] + rq[1] + rq[2] + rq[3];
  const float mu = s * (1.f / D_);
  const float var = q * (1.f / D_) - mu * mu;
  const float rstd = rsqrtf(var + 1e-5f);
#pragma unroll
  for (int i = 0; i < 4; ++i) {
    const float r = (v[i] - mu) * rstd * g[t * 4 + i] + be[t * 4 + i];
    if (MODE == 0) ((bf16*)Out)[base + i] = __float2bfloat16(r);
    else           ((float*)Out)[base + i] = r;
  }
}

extern "C" void kernel_launch(void* const* d_in, const int* in_sizes, int n_in,
                              void* d_out, int out_size, void* d_ws, size_t ws_size,
                              hipStream_t stream) {
  const float* x     = (const float*)d_in[0];
  const float* qkv_b = (const float*)d_in[2];
  const float* out_b = (const float*)d_in[4];
  const float* b1    = (const float*)d_in[6];
  const float* b2    = (const float*)d_in[8];
  const float* l1w   = (const float*)d_in[9];
  const float* l1b   = (const float*)d_in[10];
  const float* l2w   = (const float*)d_in[11];
  const float* l2b   = (const float*)d_in[12];

  float* out    = (float*)d_out;
  float* kcache = out + (size_t)M_ * D_;
  float* vcache = kcache + (size_t)M_ * D_;

  // ws (bf16 elems). High-water 36M elems = 72 MB (<75 MB established safe).
  //  [0,4M)   xc      -> attnb (after QKV) -> pA fp32 partial (after outproj)
  //  [4,7M)   wqkv    -> h1 (after out-proj; h1 spans [4,8M))
  //  [7,8M)   wout
  //  [8,12M)  w1c
  //  [12,16M) w2c
  //  [16,20M) qbuf    -> y1 (after flash) -> pB fp32 partial (after ln1)
  //  [20,24M) kb      -> ffb (after flash; full ffb spans [20,36M))
  //  [24,28M) vb
  bf16* ws    = (bf16*)d_ws;
  bf16* xc    = ws;
  bf16* attnb = ws;
  bf16* wqkv  = ws + 4 * MEG;
  bf16* h1    = ws + 4 * MEG;
  bf16* wout  = ws + 7 * MEG;
  bf16* w1c   = ws + 8 * MEG;
  bf16* w2c   = ws + 12 * MEG;
  bf16* qbuf  = ws + 16 * MEG;
  bf16* y1    = ws + 16 * MEG;
  bf16* kb    = ws + 20 * MEG;
  bf16* ffb   = ws + 20 * MEG;
  bf16* vb    = ws + 24 * MEG;
  float* pA   = (float*)ws;               // rows 0..2047  K-half-1 partial
  float* pB   = (float*)(ws + 16 * MEG);  // rows 2048..4095

  const dim3 blk(256);

  // all 5 fp32->bf16 conversions in one dispatch
  CvtArgs ca;
  ca.src[0] = x;                    ca.dst[0] = xc;   ca.n[0] = M_ * D_;
  ca.src[1] = (const float*)d_in[1]; ca.dst[1] = wqkv; ca.n[1] = 3 * D_ * D_;
  ca.src[2] = (const float*)d_in[3]; ca.dst[2] = wout; ca.n[2] = D_ * D_;
  ca.src[3] = (const float*)d_in[5]; ca.dst[3] = w1c;  ca.n[3] = FFD_ * D_;
  ca.src[4] = (const float*)d_in[7]; ca.dst[4] = w2c;  ca.n[4] = D_ * FFD_;
  cvt_f2b_multi<<<dim3((M_ * D_ + 2047) / 2048, 5), blk, 0, stream>>>(ca);

  // QKV: q (pre-scaled 0.125) -> qbuf bf16; k/v->fp32 caches + bf16 ws copies.
  gemm_bt<3><<<dim3(3 * D_ / 128, M_ / 128), blk, 0, stream>>>(
      xc, wqkv, qkv_b, qbuf, nullptr, kcache, kb, vcache, vb, nullptr,
      M_, 3 * D_, D_);
  flash_attn<<<dim3(S_ / 128, H_, B_), blk, 0, stream>>>(qbuf, kb, vb, attnb);
  // out-proj -> y1 bf16 (overwrites dead qbuf)
  gemm_bt<0><<<dim3(D_ / 128, M_ / 128), blk, 0, stream>>>(
      attnb, wout, out_b, y1, nullptr, nullptr, nullptr, nullptr, nullptr,
      nullptr, M_, D_, D_);
  // h1 = LN(x + y1) -> bf16 (overwrites dead wqkv)
  add_ln<0><<<dim3(M_), blk, 0, stream>>>(x, y1, nullptr, nullptr, l1w, l1b, h1);
  // MLP full-M: MLP1 -> ffb [20,36M); MLP2 split-K=2 + BK=64:
  // z=0 K-half-0 + bias + resid -> out; z=1 K-half-1 raw -> pA/pB.
  gemm_bt<1><<<dim3(FFD_ / 128, M_ / 128), blk, 0, stream>>>(
      h1, w1c, b1, ffb, nullptr, nullptr, nullptr, nullptr, nullptr,
      nullptr, M_, FFD_, D_);
  gemm_bt<2><<<dim3(D_ / 128, M_ / 128, 2), blk, 0, stream>>>(
      ffb, w2c, b2, nullptr, out, pA, nullptr, pB, nullptr,
      h1, M_, D_, FFD_);
  // out = LN(out + partial) in place, fp32.
  add_ln<1><<<dim3(M_), blk, 0, stream>>>(out, nullptr, pA, pB, l2w, l2b, out);
}

// Round 9
// 362.567 us; speedup vs baseline: 1.0765x; 1.0262x over previous
//
#include <hip/hip_runtime.h>
#include <hip/hip_bf16.h>
#include <stdint.h>

typedef __hip_bfloat16 bf16;
typedef __attribute__((ext_vector_type(8))) short s16x8;
typedef __attribute__((ext_vector_type(4))) float f32x4;

#define B_   2
#define S_   2048
#define D_   1024
#define H_   16
#define HD_  64
#define FFD_ 4096
#define M_   4096
#define MEG  ((size_t)1048576)

__device__ __forceinline__ f32x4 mfma_bf16(s16x8 a, s16x8 b, f32x4 c) {
  return __builtin_amdgcn_mfma_f32_16x16x32_bf16(a, b, c, 0, 0, 0);
}

__device__ __forceinline__ void gl_lds16(const bf16* g, bf16* l) {
  __builtin_amdgcn_global_load_lds(
      (const __attribute__((address_space(1))) void*)g,
      (__attribute__((address_space(3))) void*)l, 16, 0, 0);
}

__device__ __forceinline__ float b2f(short u) {
  union { uint32_t i; float f; } z;
  z.i = ((uint32_t)(unsigned short)u) << 16;
  return z.f;
}
__device__ __forceinline__ short f2b(float f) {
  const bf16 h = __float2bfloat16(f);
  return *(const short*)&h;
}

// ---------------------------------------------------------------------------
// fp32 -> bf16 conversion, all 5 tensors in ONE dispatch (z-indexed).
// ---------------------------------------------------------------------------
struct CvtArgs {
  const float* src[5];
  bf16* dst[5];
  int n[5];
};
__global__ __launch_bounds__(256) void cvt_f2b_multi(CvtArgs a) {
  const int z = blockIdx.y;
  const int idx = (blockIdx.x * 256 + threadIdx.x) * 8;
  if (idx >= a.n[z]) return;
  const float* src = a.src[z];
  s16x8 o;
#pragma unroll
  for (int i = 0; i < 8; ++i) o[i] = f2b(src[idx + i]);
  *(s16x8*)(a.dst[z] + idx) = o;
}

// ---------------------------------------------------------------------------
// MFMA NT GEMM: C[m,n] = sum_k A[m,k]*W[n,k] + bias[n]  (bias fp32)
// 128x128 tile, 4 waves (2x2), 4x4 16x16x32 frags.
// v5: round-5 v2 loop (2-buffer gl_lds, one __syncthreads drain per K-step).
//     BK=64 for MODE 2 (2 blocks/CU grid) AND MODE 0 (1 block/CU grid) —
//     both have occupancy slack, so 64 KB LDS is free and drain events halve.
//     BK=64 chunk-XOR swizzle: LDS phys chunk c at row r holds global chunk
//     c^(r&7); read side applies ^(l15&7). Bit-identical arithmetic order.
//     T1 XCD-chunked block swizzle kept (FETCH 139->53 MB).
// MODE 0: C -> bf16 Cb             (out-proj -> y1)           [BK=64]
// MODE 1: relu, C -> bf16 Cb       (MLP1 -> ff)               [BK=32]
// MODE 2: SPLIT-K=2 (gridDim.z=2). z=0: K-half-0 + bias + resid -> fp32 Cf.
//         z=1: K-half-1 raw partial -> fp32 Kf/Vf.            [BK=64]
// MODE 3: QKV split: seg0 q*0.125 -> bf16 Cb; seg1 k->fp32 Kf + bf16 Kb;
//         seg2 v->fp32 Vf + bf16 Vb.                          [BK=32]
// ---------------------------------------------------------------------------
template <int MODE>
__global__ __launch_bounds__(256) void gemm_bt(
    const bf16* __restrict__ A, const bf16* __restrict__ W,
    const float* __restrict__ bias,
    bf16* __restrict__ Cb, float* __restrict__ Cf,
    float* __restrict__ Kf, bf16* __restrict__ Kb,
    float* __restrict__ Vf, bf16* __restrict__ Vb,
    const bf16* __restrict__ Res,
    int M, int N, int K) {
  constexpr int BK = (MODE == 2 || MODE == 0) ? 64 : 32;
  __shared__ __align__(16) bf16 As[2][128 * BK];
  __shared__ __align__(16) bf16 Bs[2][128 * BK];
  const int t = threadIdx.x;

  // T1 XCD-chunked swizzle (all grids have nwg % 8 == 0 -> bijective).
  const int nwg = gridDim.x * gridDim.y;
  const int bid = blockIdx.y * gridDim.x + blockIdx.x;
  const int sw  = (bid & 7) * (nwg >> 3) + (bid >> 3);
  const int m0 = (sw / gridDim.x) << 7, n0 = (sw % gridDim.x) << 7;

  const int w = t >> 6, l = t & 63;
  const int wm = (w >> 1) << 6, wn = (w & 1) << 6;
  const int l15 = l & 15, quad = l >> 4;

  const int kz   = (MODE == 2) ? (int)blockIdx.z : 0;   // K-split index
  const int Keff = (MODE == 2) ? (K >> 1) : K;

  f32x4 acc[4][4] = {};

  // staging addresses
  const int srow = (BK == 32) ? (t >> 2) : (t >> 3);
  const int scol = (BK == 32) ? ((t & 3) << 3)
                              : (((t & 7) ^ ((t >> 3) & 7)) << 3);  // pre-swz
  const bf16* Ag  = A + (size_t)(m0 + srow) * K + kz * Keff + scol;
  const bf16* Ag2 = Ag + ((size_t)K << 6);   // +64 rows (BK=32 path)
  const bf16* Wg  = W + (size_t)(n0 + srow) * K + kz * Keff + scol;
  const bf16* Wg2 = Wg + ((size_t)K << 6);

#define STAGE_G(KI, BUF) do {                                                \
    if constexpr (BK == 32) {                                                \
      const int ko_ = (KI) * 32;                                             \
      gl_lds16(Ag + ko_, (bf16*)As[BUF] + t * 8);                            \
      gl_lds16(Ag2 + ko_, (bf16*)As[BUF] + 2048 + t * 8);                    \
      gl_lds16(Wg + ko_, (bf16*)Bs[BUF] + t * 8);                            \
      gl_lds16(Wg2 + ko_, (bf16*)Bs[BUF] + 2048 + t * 8);                    \
    } else {                                                                 \
      const int ko_ = (KI) * 64;                                             \
      _Pragma("unroll") for (int i_ = 0; i_ < 4; ++i_) {                     \
        gl_lds16(Ag + ko_ + (size_t)32 * K * i_,                             \
                 (bf16*)As[BUF] + i_ * 2048 + t * 8);                        \
        gl_lds16(Wg + ko_ + (size_t)32 * K * i_,                             \
                 (bf16*)Bs[BUF] + i_ * 2048 + t * 8);                        \
      }                                                                      \
    }                                                                        \
  } while (0)

  const int nk = Keff / BK;
  STAGE_G(0, 0);
  __syncthreads();

  for (int ki = 0; ki < nk; ++ki) {
    const int cur = ki & 1;
    if (ki + 1 < nk) STAGE_G(ki + 1, cur ^ 1);

    const s16x8* As8 = (const s16x8*)As[cur];
    const s16x8* Bs8 = (const s16x8*)Bs[cur];
    if constexpr (BK == 32) {
      s16x8 af[4], bfr[4];
#pragma unroll
      for (int i = 0; i < 4; ++i) af[i]  = As8[((wm + i * 16 + l15) << 2) + quad];
#pragma unroll
      for (int i = 0; i < 4; ++i) bfr[i] = Bs8[((wn + i * 16 + l15) << 2) + quad];
      __builtin_amdgcn_s_setprio(1);
#pragma unroll
      for (int mi = 0; mi < 4; ++mi)
#pragma unroll
        for (int ni = 0; ni < 4; ++ni)
          acc[mi][ni] = mfma_bf16(af[mi], bfr[ni], acc[mi][ni]);
      __builtin_amdgcn_s_setprio(0);
    } else {
      const int sx = l15 & 7;
#pragma unroll
      for (int h = 0; h < 2; ++h) {
        s16x8 af[4], bfr[4];
#pragma unroll
        for (int i = 0; i < 4; ++i)
          af[i]  = As8[((wm + i * 16 + l15) << 3) + ((h * 4 + quad) ^ sx)];
#pragma unroll
        for (int i = 0; i < 4; ++i)
          bfr[i] = Bs8[((wn + i * 16 + l15) << 3) + ((h * 4 + quad) ^ sx)];
        __builtin_amdgcn_s_setprio(1);
#pragma unroll
        for (int mi = 0; mi < 4; ++mi)
#pragma unroll
          for (int ni = 0; ni < 4; ++ni)
            acc[mi][ni] = mfma_bf16(af[mi], bfr[ni], acc[mi][ni]);
        __builtin_amdgcn_s_setprio(0);
      }
    }
    __syncthreads();
  }
#undef STAGE_G

  float bv[4];
#pragma unroll
  for (int ni = 0; ni < 4; ++ni)
    bv[ni] = bias[n0 + wn + ni * 16 + l15];

  const int seg = n0 >> 10, nb2 = n0 & 1023;
#pragma unroll
  for (int mi = 0; mi < 4; ++mi) {
#pragma unroll
    for (int reg = 0; reg < 4; ++reg) {
      const int row = m0 + wm + mi * 16 + quad * 4 + reg;
#pragma unroll
      for (int ni = 0; ni < 4; ++ni) {
        float v = acc[mi][ni][reg] + ((MODE == 2 && kz) ? 0.f : bv[ni]);
        if (MODE == 0) {
          Cb[(size_t)row * N + n0 + wn + ni * 16 + l15] = __float2bfloat16(v);
        } else if (MODE == 1) {
          v = fmaxf(v, 0.f);
          Cb[(size_t)row * N + n0 + wn + ni * 16 + l15] = __float2bfloat16(v);
        } else if (MODE == 2) {
          const size_t col = n0 + wn + ni * 16 + l15;
          if (kz == 0) {
            const size_t o = (size_t)row * N + col;
            Cf[o] = v + b2f(*(const short*)&Res[o]);
          } else {
            float* P = (row < 2048) ? Kf : Vf;   // partial bufs (dead ws)
            P[(size_t)(row & 2047) * N + col] = v;
          }
        } else {  // MODE 3
          const size_t o = (size_t)row * 1024 + nb2 + wn + ni * 16 + l15;
          if (seg == 0) {
            Cb[o] = __float2bfloat16(v * 0.125f);   // pre-scale Q by 1/sqrt(hd)
          } else if (seg == 1) {
            Kf[o] = v; Kb[o] = __float2bfloat16(v);
          } else {
            Vf[o] = v; Vb[o] = __float2bfloat16(v);
          }
        }
      }
    }
  }
}

// ---------------------------------------------------------------------------
// MFMA flash attention v6, causal, hd=64.
// Block = (q-tile PAIR {bxp, 31-bxp}, head, batch): every block does exactly
// 33 k-tiles -> perfect inter-CU balance. Grid 512 blocks, 2/CU.
// XCD-locality decode (v5, verified: FETCH 122->12.4 MB, K/V L2-resident).
// v6: CHEAP DEFER-MAX GATE — common path computes only the lane-local max
//     (3 fmax/reg) and tests lmax > m_i+8 via __any; row-max > thr iff some
//     lane-max > thr, so the rescale DECISION is identical, but the
//     16-shuffle cross-lane reduce moves inside the rare rescale branch.
//     Removes 4 dependent DS-latency rounds from every tile's critical path.
//     + T5 setprio(1) around QK and PV MFMA clusters.
// ---------------------------------------------------------------------------
#define BAR_SYNC() do {                                                      \
    asm volatile("s_waitcnt lgkmcnt(0)" ::: "memory");                       \
    __builtin_amdgcn_s_barrier();                                            \
    __builtin_amdgcn_sched_barrier(0);                                       \
  } while (0)

#define ISSUE(KT) do { const size_t ko_ = (size_t)((KT) << 6) * D_;          \
    kr0 = *(const s16x8*)(Kg + ko_);                                         \
    kr1 = *(const s16x8*)(Kg2 + ko_);                                        \
    vr0 = *(const s16x8*)(Vg + ko_);                                         \
    vr1 = *(const s16x8*)(Vg + ko_ + 8);                                     \
  } while (0)

#define WRITEKV(KT) do {                                                     \
    bf16* kd_ = Ks[(KT) & 1];                                                \
    *(s16x8*)&kd_[krow * 64 + (kchunk << 3)] = kr0;                          \
    *(s16x8*)&kd_[(krow + 32) * 64 + (kchunk << 3)] = kr1;                   \
    short* vp_ = (short*)Vt[(KT) & 1];                                       \
    _Pragma("unroll") for (int j = 0; j < 8; ++j) {                          \
      const int d0_ = vd + j, d1_ = vd + 8 + j;                              \
      vp_[d0_ * 64 + (vk ^ ((d0_ & 7) << 3))] = vr0[j];                      \
      vp_[d1_ * 64 + (vk ^ ((d1_ & 7) << 3))] = vr1[j];                      \
    }                                                                        \
  } while (0)

#define QK_LOAD(KT) do { const bf16* Kq_ = Ks[(KT) & 1];                     \
    ka0 = *(const s16x8*)&Kq_[( 0 + l15) * 64 + (( 0 + quad * 8) ^ swr)];    \
    ka1 = *(const s16x8*)&Kq_[(16 + l15) * 64 + (( 0 + quad * 8) ^ swr)];    \
    ka2 = *(const s16x8*)&Kq_[(32 + l15) * 64 + (( 0 + quad * 8) ^ swr)];    \
    ka3 = *(const s16x8*)&Kq_[(48 + l15) * 64 + (( 0 + quad * 8) ^ swr)];    \
    kb0 = *(const s16x8*)&Kq_[( 0 + l15) * 64 + ((32 + quad * 8) ^ swr)];    \
    kb1 = *(const s16x8*)&Kq_[(16 + l15) * 64 + ((32 + quad * 8) ^ swr)];    \
    kb2 = *(const s16x8*)&Kq_[(32 + l15) * 64 + ((32 + quad * 8) ^ swr)];    \
    kb3 = *(const s16x8*)&Kq_[(48 + l15) * 64 + ((32 + quad * 8) ^ swr)];    \
  } while (0)

#define QK_MFMA(S0_, S1_, S2_, S3_) do {                                     \
    __builtin_amdgcn_s_setprio(1);                                           \
    f32x4 z_ = {};                                                           \
    z_ = mfma_bf16(qf0, ka0, z_); S0_ = mfma_bf16(qf1, kb0, z_);             \
    z_ = (f32x4){};                                                          \
    z_ = mfma_bf16(qf0, ka1, z_); S1_ = mfma_bf16(qf1, kb1, z_);             \
    z_ = (f32x4){};                                                          \
    z_ = mfma_bf16(qf0, ka2, z_); S2_ = mfma_bf16(qf1, kb2, z_);             \
    z_ = (f32x4){};                                                          \
    z_ = mfma_bf16(qf0, ka3, z_); S3_ = mfma_bf16(qf1, kb3, z_);             \
    __builtin_amdgcn_s_setprio(0);                                           \
  } while (0)

#define SMAXPV(J, S0_, S1_, S2_, S3_) do {                                   \
    if ((J) == nt - 1) {  /* diagonal tile only */                           \
      _Pragma("unroll") for (int reg = 0; reg < 4; ++reg) {                  \
        const int qrow_ = qb + (w << 4) + quad * 4 + reg;                    \
        const int k0_ = ((J) << 6) + l15;                                    \
        if (k0_ +  0 > qrow_) S0_[reg] = -1e30f;                             \
        if (k0_ + 16 > qrow_) S1_[reg] = -1e30f;                             \
        if (k0_ + 32 > qrow_) S2_[reg] = -1e30f;                             \
        if (k0_ + 48 > qrow_) S3_[reg] = -1e30f;                             \
      }                                                                      \
    }                                                                        \
    float lm_[4];  /* lane-local max only (cheap defer-max gate) */          \
    _Pragma("unroll") for (int reg = 0; reg < 4; ++reg)                      \
      lm_[reg] = fmaxf(fmaxf(S0_[reg], S1_[reg]), fmaxf(S2_[reg], S3_[reg]));\
    bool up_ = false;                                                        \
    _Pragma("unroll") for (int reg = 0; reg < 4; ++reg)                      \
      up_ = up_ || (lm_[reg] > m_i[reg] + 8.f);                              \
    if (__any(up_)) {  /* rare: full reduce + rescale (T13) */               \
      float mx_[4];                                                          \
      _Pragma("unroll") for (int reg = 0; reg < 4; ++reg) mx_[reg] = lm_[reg];\
      _Pragma("unroll") for (int off = 1; off < 16; off <<= 1)               \
        _Pragma("unroll") for (int reg = 0; reg < 4; ++reg)                  \
          mx_[reg] = fmaxf(mx_[reg], __shfl_xor(mx_[reg], off, 64));         \
      _Pragma("unroll") for (int reg = 0; reg < 4; ++reg) {                  \
        const float nm_ = fmaxf(m_i[reg], mx_[reg]);                         \
        const float al_ = __expf(m_i[reg] - nm_);                            \
        m_i[reg] = nm_; l_p[reg] *= al_;                                     \
        o[0][reg] *= al_; o[1][reg] *= al_;                                  \
        o[2][reg] *= al_; o[3][reg] *= al_;                                  \
      }                                                                      \
    }                                                                        \
    _Pragma("unroll") for (int reg = 0; reg < 4; ++reg) {                    \
      const float e0_ = __expf(S0_[reg] - m_i[reg]);                         \
      const float e1_ = __expf(S1_[reg] - m_i[reg]);                         \
      const float e2_ = __expf(S2_[reg] - m_i[reg]);                         \
      const float e3_ = __expf(S3_[reg] - m_i[reg]);                         \
      l_p[reg] += e0_ + e1_ + e2_ + e3_;                                     \
      const int row_ = quad * 4 + reg;                                       \
      bf16* pr_ = &Ps[w][row_ * 64];                                         \
      const int sx_ = (row_ & 7) << 3;                                       \
      pr_[( 0 + l15) ^ sx_] = __float2bfloat16(e0_);                         \
      pr_[(16 + l15) ^ sx_] = __float2bfloat16(e1_);                         \
      pr_[(32 + l15) ^ sx_] = __float2bfloat16(e2_);                         \
      pr_[(48 + l15) ^ sx_] = __float2bfloat16(e3_);                         \
    }                                                                        \
    {                                                                        \
      const bf16* Vc_ = Vt[(J) & 1];                                         \
      _Pragma("unroll") for (int ks = 0; ks < 2; ++ks) {                     \
        const s16x8 pf_ =                                                    \
            *(const s16x8*)&Ps[w][l15 * 64 + ((ks * 32 + quad * 8) ^ swr)];  \
        __builtin_amdgcn_s_setprio(1);                                       \
        _Pragma("unroll") for (int ni = 0; ni < 4; ++ni) {                   \
          const s16x8 vf_ = *(const s16x8*)                                  \
              &Vc_[(ni * 16 + l15) * 64 + ((ks * 32 + quad * 8) ^ swr)];     \
          o[ni] = mfma_bf16(pf_, vf_, o[ni]);                                \
        }                                                                    \
        __builtin_amdgcn_s_setprio(0);                                       \
      }                                                                      \
    }                                                                        \
  } while (0)

#define BODY(KT, SO0, SO1, SO2, SO3, SN0, SN1, SN2, SN3) do {                \
    WRITEKV(KT);                                                             \
    BAR_SYNC();                                                              \
    if ((KT) + 1 < nt) ISSUE((KT) + 1);                                      \
    QK_LOAD(KT);                                                             \
    QK_MFMA(SN0, SN1, SN2, SN3);                                             \
    SMAXPV((KT) - 1, SO0, SO1, SO2, SO3);                                    \
    BAR_SYNC();                                                              \
  } while (0)

__global__ __launch_bounds__(256, 2) void flash_attn(
    const bf16* __restrict__ Q, const bf16* __restrict__ Kk,
    const bf16* __restrict__ V, bf16* __restrict__ O) {
  // XCD-locality decode: all 16 pair-blocks of one (h,b) -> same XCD.
  const int lin = (int)(blockIdx.x + 16 * blockIdx.y + 256 * blockIdx.z);
  const int xcd = lin & 7;
  const int slot = lin >> 3;                  // 0..63
  const int bxp = slot >> 2;                  // 0..15: q-tile pair id
  const int g = xcd + ((slot & 3) << 3);      // 0..31: (h,b) group
  const int h = g & 15, b = g >> 4;

  const int t = threadIdx.x, w = t >> 6, l = t & 63;
  const int l15 = l & 15, quad = l >> 4;
  __shared__ __align__(16) bf16 Ks[2][64 * 64];    // [buf][key][d] swizzled
  __shared__ __align__(16) bf16 Vt[2][64 * 64];    // [buf][d][key] swizzled
  __shared__ __align__(16) bf16 Ps[4][16 * 64];    // per-wave P, swizzled

  // K staging: linear global chunk; swizzle applied at ds_write dest.
  const int krow = t >> 3;                    // 0..31
  const int kchunk = (t & 7) ^ (krow & 7);    // swizzled LDS chunk
  const bf16* Kg  = Kk + (size_t)(b * S_ + krow) * D_ + h * HD_ + ((t & 7) << 3);
  const bf16* Kg2 = Kg + (size_t)32 * D_;
  const int vk = t & 63, vd = w << 4;
  const bf16* Vg = V + (size_t)(b * S_ + vk) * D_ + h * HD_ + vd;
  const int swr = (l15 & 7) << 3;             // read-side xor (elements)

  s16x8 kr0, kr1, vr0, vr1;                   // staging regs (1 tile)
  s16x8 ka0, ka1, ka2, ka3, kb0, kb1, kb2, kb3;  // K fragment regs

#pragma unroll 1
  for (int ph = 0; ph < 2; ++ph) {
    const int qt = ph ? (S_ / 64 - 1 - bxp) : bxp;
    const int qb = qt << 6;
    const int nt = qt + 1;

    __syncthreads();   // protect LDS reuse across phases (full drain, 2x total)

    const bf16* qp =
        Q + (size_t)(b * S_ + qb + (w << 4) + l15) * D_ + h * HD_ + quad * 8;
    const s16x8 qf0 = *(const s16x8*)qp;
    const s16x8 qf1 = *(const s16x8*)(qp + 32);

    f32x4 o[4] = {};
    float m_i[4], l_p[4];
#pragma unroll
    for (int r = 0; r < 4; ++r) { m_i[r] = -1e30f; l_p[r] = 0.f; }

    f32x4 sA0, sA1, sA2, sA3, sB0, sB1, sB2, sB3;

    // ---- prologue: tile 0 ----
    ISSUE(0);
    WRITEKV(0);                  // counted vmcnt waits for kr/vr (cold, once)
    BAR_SYNC();
    if (nt > 1) ISSUE(1);
    QK_LOAD(0);
    QK_MFMA(sA0, sA1, sA2, sA3);
    BAR_SYNC();

    // ---- main loop: 2-stage score pipeline, hand-unrolled ping-pong ----
    int kt = 1;
    for (; kt + 1 < nt; kt += 2) {
      BODY(kt,     sA0, sA1, sA2, sA3, sB0, sB1, sB2, sB3);
      BODY(kt + 1, sB0, sB1, sB2, sB3, sA0, sA1, sA2, sA3);
    }
    if (kt < nt) {
      BODY(kt, sA0, sA1, sA2, sA3, sB0, sB1, sB2, sB3);
      SMAXPV(nt - 1, sB0, sB1, sB2, sB3);
    } else {
      SMAXPV(nt - 1, sA0, sA1, sA2, sA3);
    }

    // ---- epilogue: deferred l reduction + O write ----
    float inv[4];
#pragma unroll
    for (int off = 1; off < 16; off <<= 1)
#pragma unroll
      for (int reg = 0; reg < 4; ++reg)
        l_p[reg] += __shfl_xor(l_p[reg], off, 64);
#pragma unroll
    for (int reg = 0; reg < 4; ++reg) inv[reg] = 1.f / l_p[reg];

#pragma unroll
    for (int reg = 0; reg < 4; ++reg) {
      const int row = b * S_ + qb + (w << 4) + quad * 4 + reg;
      bf16* op = O + (size_t)row * D_ + h * HD_ + l15;
#pragma unroll
      for (int ni = 0; ni < 4; ++ni)
        op[ni * 16] = __float2bfloat16(o[ni][reg] * inv[reg]);
    }
  }
}

// ---------------------------------------------------------------------------
// LN1 (MODE 0): h1 = LN(x_f32 + y1_bf16) -> bf16.
// LN2 (MODE 1): out = LN(X + PA/PB partial) -> fp32 in place (X=out holds
//               K-half-0 + bias + resid; PA/PB hold K-half-1 partial).
// One block per 1024-col row.
// ---------------------------------------------------------------------------
template <int MODE>   // 0: LN1, 1: LN2
__global__ __launch_bounds__(256) void add_ln(
    const float* __restrict__ X, const bf16* __restrict__ Y,
    const float* __restrict__ PA, const float* __restrict__ PB,
    const float* __restrict__ g, const float* __restrict__ be,
    void* Out) {
  const int row = blockIdx.x, t = threadIdx.x;
  const size_t base = (size_t)row * D_ + t * 4;
  const float* P = (MODE == 1)
      ? ((row < 2048) ? PA + base : PB + (base - (size_t)2048 * D_))
      : nullptr;
  float v[4];
  float s = 0.f, q = 0.f;
#pragma unroll
  for (int i = 0; i < 4; ++i) {
    v[i] = X[base + i];
    if (MODE == 0) v[i] += b2f(*(const short*)&Y[base + i]);
    else           v[i] += P[i];
    s += v[i];
    q += v[i] * v[i];
  }
#pragma unroll
  for (int off = 32; off; off >>= 1) {
    s += __shfl_down(s, off, 64);
    q += __shfl_down(q, off, 64);
  }
  __shared__ float rs[4], rq[4];
  const int w = t >> 6, l = t & 63;
  if (l == 0) { rs[w] = s; rq[w] = q; }
  __syncthreads();
  s = rs[0] + rs[1] + rs[2] + rs[3];
  q = rq[0] + rq[1] + rq[2] + rq[3];
  const float mu = s * (1.f / D_);
  const float var = q * (1.f / D_) - mu * mu;
  const float rstd = rsqrtf(var + 1e-5f);
#pragma unroll
  for (int i = 0; i < 4; ++i) {
    const float r = (v[i] - mu) * rstd * g[t * 4 + i] + be[t * 4 + i];
    if (MODE == 0) ((bf16*)Out)[base + i] = __float2bfloat16(r);
    else           ((float*)Out)[base + i] = r;
  }
}

extern "C" void kernel_launch(void* const* d_in, const int* in_sizes, int n_in,
                              void* d_out, int out_size, void* d_ws, size_t ws_size,
                              hipStream_t stream) {
  const float* x     = (const float*)d_in[0];
  const float* qkv_b = (const float*)d_in[2];
  const float* out_b = (const float*)d_in[4];
  const float* b1    = (const float*)d_in[6];
  const float* b2    = (const float*)d_in[8];
  const float* l1w   = (const float*)d_in[9];
  const float* l1b   = (const float*)d_in[10];
  const float* l2w   = (const float*)d_in[11];
  const float* l2b   = (const float*)d_in[12];

  float* out    = (float*)d_out;
  float* kcache = out + (size_t)M_ * D_;
  float* vcache = kcache + (size_t)M_ * D_;

  // ws (bf16 elems). High-water 36M elems = 72 MB (<75 MB established safe).
  //  [0,4M)   xc      -> attnb (after QKV) -> pA fp32 partial (after outproj)
  //  [4,7M)   wqkv    -> h1 (after out-proj; h1 spans [4,8M))
  //  [7,8M)   wout
  //  [8,12M)  w1c
  //  [12,16M) w2c
  //  [16,20M) qbuf    -> y1 (after flash) -> pB fp32 partial (after ln1)
  //  [20,24M) kb      -> ffb (after flash; full ffb spans [20,36M))
  //  [24,28M) vb
  bf16* ws    = (bf16*)d_ws;
  bf16* xc    = ws;
  bf16* attnb = ws;
  bf16* wqkv  = ws + 4 * MEG;
  bf16* h1    = ws + 4 * MEG;
  bf16* wout  = ws + 7 * MEG;
  bf16* w1c   = ws + 8 * MEG;
  bf16* w2c   = ws + 12 * MEG;
  bf16* qbuf  = ws + 16 * MEG;
  bf16* y1    = ws + 16 * MEG;
  bf16* kb    = ws + 20 * MEG;
  bf16* ffb   = ws + 20 * MEG;
  bf16* vb    = ws + 24 * MEG;
  float* pA   = (float*)ws;               // rows 0..2047  K-half-1 partial
  float* pB   = (float*)(ws + 16 * MEG);  // rows 2048..4095

  const dim3 blk(256);

  // all 5 fp32->bf16 conversions in one dispatch
  CvtArgs ca;
  ca.src[0] = x;                    ca.dst[0] = xc;   ca.n[0] = M_ * D_;
  ca.src[1] = (const float*)d_in[1]; ca.dst[1] = wqkv; ca.n[1] = 3 * D_ * D_;
  ca.src[2] = (const float*)d_in[3]; ca.dst[2] = wout; ca.n[2] = D_ * D_;
  ca.src[3] = (const float*)d_in[5]; ca.dst[3] = w1c;  ca.n[3] = FFD_ * D_;
  ca.src[4] = (const float*)d_in[7]; ca.dst[4] = w2c;  ca.n[4] = D_ * FFD_;
  cvt_f2b_multi<<<dim3((M_ * D_ + 2047) / 2048, 5), blk, 0, stream>>>(ca);

  // QKV: q (pre-scaled 0.125) -> qbuf bf16; k/v->fp32 caches + bf16 ws copies.
  gemm_bt<3><<<dim3(3 * D_ / 128, M_ / 128), blk, 0, stream>>>(
      xc, wqkv, qkv_b, qbuf, nullptr, kcache, kb, vcache, vb, nullptr,
      M_, 3 * D_, D_);
  flash_attn<<<dim3(S_ / 128, H_, B_), blk, 0, stream>>>(qbuf, kb, vb, attnb);
  // out-proj -> y1 bf16 (overwrites dead qbuf)
  gemm_bt<0><<<dim3(D_ / 128, M_ / 128), blk, 0, stream>>>(
      attnb, wout, out_b, y1, nullptr, nullptr, nullptr, nullptr, nullptr,
      nullptr, M_, D_, D_);
  // h1 = LN(x + y1) -> bf16 (overwrites dead wqkv)
  add_ln<0><<<dim3(M_), blk, 0, stream>>>(x, y1, nullptr, nullptr, l1w, l1b, h1);
  // MLP full-M: MLP1 -> ffb [20,36M); MLP2 split-K=2 + BK=64:
  // z=0 K-half-0 + bias + resid -> out; z=1 K-half-1 raw -> pA/pB.
  gemm_bt<1><<<dim3(FFD_ / 128, M_ / 128), blk, 0, stream>>>(
      h1, w1c, b1, ffb, nullptr, nullptr, nullptr, nullptr, nullptr,
      nullptr, M_, FFD_, D_);
  gemm_bt<2><<<dim3(D_ / 128, M_ / 128, 2), blk, 0, stream>>>(
      ffb, w2c, b2, nullptr, out, pA, nullptr, pB, nullptr,
      h1, M_, D_, FFD_);
  // out = LN(out + partial) in place, fp32.
  add_ln<1><<<dim3(M_), blk, 0, stream>>>(out, nullptr, pA, pB, l2w, l2b, out);
}

// Round 10
// 359.547 us; speedup vs baseline: 1.0855x; 1.0084x over previous
//
#include <hip/hip_runtime.h>
#include <hip/hip_bf16.h>
#include <stdint.h>

typedef __hip_bfloat16 bf16;
typedef __attribute__((ext_vector_type(8))) short s16x8;
typedef __attribute__((ext_vector_type(4))) float f32x4;

#define B_   2
#define S_   2048
#define D_   1024
#define H_   16
#define HD_  64
#define FFD_ 4096
#define M_   4096
#define MEG  ((size_t)1048576)

__device__ __forceinline__ f32x4 mfma_bf16(s16x8 a, s16x8 b, f32x4 c) {
  return __builtin_amdgcn_mfma_f32_16x16x32_bf16(a, b, c, 0, 0, 0);
}

__device__ __forceinline__ void gl_lds16(const bf16* g, bf16* l) {
  __builtin_amdgcn_global_load_lds(
      (const __attribute__((address_space(1))) void*)g,
      (__attribute__((address_space(3))) void*)l, 16, 0, 0);
}

__device__ __forceinline__ float b2f(short u) {
  union { uint32_t i; float f; } z;
  z.i = ((uint32_t)(unsigned short)u) << 16;
  return z.f;
}
__device__ __forceinline__ short f2b(float f) {
  const bf16 h = __float2bfloat16(f);
  return *(const short*)&h;
}

// ---------------------------------------------------------------------------
// fp32 -> bf16 conversion, all 5 tensors in ONE dispatch (z-indexed).
// ---------------------------------------------------------------------------
struct CvtArgs {
  const float* src[5];
  bf16* dst[5];
  int n[5];
};
__global__ __launch_bounds__(256) void cvt_f2b_multi(CvtArgs a) {
  const int z = blockIdx.y;
  const int idx = (blockIdx.x * 256 + threadIdx.x) * 8;
  if (idx >= a.n[z]) return;
  const float* src = a.src[z];
  s16x8 o;
#pragma unroll
  for (int i = 0; i < 8; ++i) o[i] = f2b(src[idx + i]);
  *(s16x8*)(a.dst[z] + idx) = o;
}

// ---------------------------------------------------------------------------
// MFMA NT GEMM: C[m,n] = sum_k A[m,k]*W[n,k] + bias[n]  (bias fp32)
// 128x128 tile, 4 waves (2x2), 4x4 16x16x32 frags.
// v6: round-9 v5 kept (2-buffer gl_lds, one drain per K-step; BK=64 for
//     MODE 0/2; setprio).  NEW: MODE 1 uses a 2D XCD chunk — each XCD owns
//     a 16m x 8n tile rectangle (2x4 XCD grid) instead of 4m x 32n, cutting
//     the per-XCD working set 9 MB -> 6 MB (L2 is 4 MB) and W refetch
//     64 MB -> 16 MB (FETCH was 69.8 MB vs 16 MB logical).
//     Note: SQ_LDS_BANK_CONFLICT == 4194304 is the structural gl_lds
//     wide-write serialization (131072 ops x 32), NOT read conflicts.
// MODE 0: C -> bf16 Cb             (out-proj -> y1)           [BK=64]
// MODE 1: relu, C -> bf16 Cb       (MLP1 -> ff)               [BK=32, 2D XCD]
// MODE 2: SPLIT-K=2 (gridDim.z=2). z=0: K-half-0 + bias + resid -> fp32 Cf.
//         z=1: K-half-1 raw partial -> fp32 Kf/Vf.            [BK=64]
// MODE 3: QKV split: seg0 q*0.125 -> bf16 Cb; seg1 k->fp32 Kf + bf16 Kb;
//         seg2 v->fp32 Vf + bf16 Vb.                          [BK=32]
// ---------------------------------------------------------------------------
template <int MODE>
__global__ __launch_bounds__(256) void gemm_bt(
    const bf16* __restrict__ A, const bf16* __restrict__ W,
    const float* __restrict__ bias,
    bf16* __restrict__ Cb, float* __restrict__ Cf,
    float* __restrict__ Kf, bf16* __restrict__ Kb,
    float* __restrict__ Vf, bf16* __restrict__ Vb,
    const bf16* __restrict__ Res,
    int M, int N, int K) {
  constexpr int BK = (MODE == 2 || MODE == 0) ? 64 : 32;
  __shared__ __align__(16) bf16 As[2][128 * BK];
  __shared__ __align__(16) bf16 Bs[2][128 * BK];
  const int t = threadIdx.x;

  const int bid = blockIdx.y * gridDim.x + blockIdx.x;
  int m0, n0;
  if (MODE == 1) {
    // 2D XCD chunk: grid fixed 32x32; XCD (bid&7) -> 2x4 rect of 16m x 8n.
    const int xcd = bid & 7, idx = bid >> 3;        // idx 0..127
    const int xr = xcd >> 2, xc2 = xcd & 3;
    const int mloc = idx & 15, nloc = idx >> 4;     // walk m fast (share W)
    m0 = ((xr << 4) + mloc) << 7;
    n0 = ((xc2 << 3) + nloc) << 7;
  } else {
    // 1D T1 XCD-chunked swizzle (nwg % 8 == 0 -> bijective).
    const int nwg = gridDim.x * gridDim.y;
    const int sw  = (bid & 7) * (nwg >> 3) + (bid >> 3);
    m0 = (sw / gridDim.x) << 7;
    n0 = (sw % gridDim.x) << 7;
  }

  const int w = t >> 6, l = t & 63;
  const int wm = (w >> 1) << 6, wn = (w & 1) << 6;
  const int l15 = l & 15, quad = l >> 4;

  const int kz   = (MODE == 2) ? (int)blockIdx.z : 0;   // K-split index
  const int Keff = (MODE == 2) ? (K >> 1) : K;

  f32x4 acc[4][4] = {};

  // staging addresses
  const int srow = (BK == 32) ? (t >> 2) : (t >> 3);
  const int scol = (BK == 32) ? ((t & 3) << 3)
                              : (((t & 7) ^ ((t >> 3) & 7)) << 3);  // pre-swz
  const bf16* Ag  = A + (size_t)(m0 + srow) * K + kz * Keff + scol;
  const bf16* Ag2 = Ag + ((size_t)K << 6);   // +64 rows (BK=32 path)
  const bf16* Wg  = W + (size_t)(n0 + srow) * K + kz * Keff + scol;
  const bf16* Wg2 = Wg + ((size_t)K << 6);

#define STAGE_G(KI, BUF) do {                                                \
    if constexpr (BK == 32) {                                                \
      const int ko_ = (KI) * 32;                                             \
      gl_lds16(Ag + ko_, (bf16*)As[BUF] + t * 8);                            \
      gl_lds16(Ag2 + ko_, (bf16*)As[BUF] + 2048 + t * 8);                    \
      gl_lds16(Wg + ko_, (bf16*)Bs[BUF] + t * 8);                            \
      gl_lds16(Wg2 + ko_, (bf16*)Bs[BUF] + 2048 + t * 8);                    \
    } else {                                                                 \
      const int ko_ = (KI) * 64;                                             \
      _Pragma("unroll") for (int i_ = 0; i_ < 4; ++i_) {                     \
        gl_lds16(Ag + ko_ + (size_t)32 * K * i_,                             \
                 (bf16*)As[BUF] + i_ * 2048 + t * 8);                        \
        gl_lds16(Wg + ko_ + (size_t)32 * K * i_,                             \
                 (bf16*)Bs[BUF] + i_ * 2048 + t * 8);                        \
      }                                                                      \
    }                                                                        \
  } while (0)

  const int nk = Keff / BK;
  STAGE_G(0, 0);
  __syncthreads();

  for (int ki = 0; ki < nk; ++ki) {
    const int cur = ki & 1;
    if (ki + 1 < nk) STAGE_G(ki + 1, cur ^ 1);

    const s16x8* As8 = (const s16x8*)As[cur];
    const s16x8* Bs8 = (const s16x8*)Bs[cur];
    if constexpr (BK == 32) {
      s16x8 af[4], bfr[4];
#pragma unroll
      for (int i = 0; i < 4; ++i) af[i]  = As8[((wm + i * 16 + l15) << 2) + quad];
#pragma unroll
      for (int i = 0; i < 4; ++i) bfr[i] = Bs8[((wn + i * 16 + l15) << 2) + quad];
      __builtin_amdgcn_s_setprio(1);
#pragma unroll
      for (int mi = 0; mi < 4; ++mi)
#pragma unroll
        for (int ni = 0; ni < 4; ++ni)
          acc[mi][ni] = mfma_bf16(af[mi], bfr[ni], acc[mi][ni]);
      __builtin_amdgcn_s_setprio(0);
    } else {
      const int sx = l15 & 7;
#pragma unroll
      for (int h = 0; h < 2; ++h) {
        s16x8 af[4], bfr[4];
#pragma unroll
        for (int i = 0; i < 4; ++i)
          af[i]  = As8[((wm + i * 16 + l15) << 3) + ((h * 4 + quad) ^ sx)];
#pragma unroll
        for (int i = 0; i < 4; ++i)
          bfr[i] = Bs8[((wn + i * 16 + l15) << 3) + ((h * 4 + quad) ^ sx)];
        __builtin_amdgcn_s_setprio(1);
#pragma unroll
        for (int mi = 0; mi < 4; ++mi)
#pragma unroll
          for (int ni = 0; ni < 4; ++ni)
            acc[mi][ni] = mfma_bf16(af[mi], bfr[ni], acc[mi][ni]);
        __builtin_amdgcn_s_setprio(0);
      }
    }
    __syncthreads();
  }
#undef STAGE_G

  float bv[4];
#pragma unroll
  for (int ni = 0; ni < 4; ++ni)
    bv[ni] = bias[n0 + wn + ni * 16 + l15];

  const int seg = n0 >> 10, nb2 = n0 & 1023;
#pragma unroll
  for (int mi = 0; mi < 4; ++mi) {
#pragma unroll
    for (int reg = 0; reg < 4; ++reg) {
      const int row = m0 + wm + mi * 16 + quad * 4 + reg;
#pragma unroll
      for (int ni = 0; ni < 4; ++ni) {
        float v = acc[mi][ni][reg] + ((MODE == 2 && kz) ? 0.f : bv[ni]);
        if (MODE == 0) {
          Cb[(size_t)row * N + n0 + wn + ni * 16 + l15] = __float2bfloat16(v);
        } else if (MODE == 1) {
          v = fmaxf(v, 0.f);
          Cb[(size_t)row * N + n0 + wn + ni * 16 + l15] = __float2bfloat16(v);
        } else if (MODE == 2) {
          const size_t col = n0 + wn + ni * 16 + l15;
          if (kz == 0) {
            const size_t o = (size_t)row * N + col;
            Cf[o] = v + b2f(*(const short*)&Res[o]);
          } else {
            float* P = (row < 2048) ? Kf : Vf;   // partial bufs (dead ws)
            P[(size_t)(row & 2047) * N + col] = v;
          }
        } else {  // MODE 3
          const size_t o = (size_t)row * 1024 + nb2 + wn + ni * 16 + l15;
          if (seg == 0) {
            Cb[o] = __float2bfloat16(v * 0.125f);   // pre-scale Q by 1/sqrt(hd)
          } else if (seg == 1) {
            Kf[o] = v; Kb[o] = __float2bfloat16(v);
          } else {
            Vf[o] = v; Vb[o] = __float2bfloat16(v);
          }
        }
      }
    }
  }
}

// ---------------------------------------------------------------------------
// MFMA flash attention v7, causal, hd=64.
// Block = (q-tile PAIR {bxp, 31-bxp}, head, batch); grid 512, 2/CU; XCD-
// locality decode (verified: FETCH 122->12.4 MB, K/V L2-resident).
// v7: 3-BUFFER K/V, SINGLE BARRIER PER TILE (was 2). Iter KT:
//   BAR; ISSUE(KT+1); QK_LOAD(KT, buf KT%3); QK_MFMA -> sNew;
//   SMAXPV(KT-1, buf (KT-1)%3, sOld); WRITEKV(KT+1 -> buf (KT+1)%3).
// Race audit: write target last read two barriers ago; QK_LOAD source
// published by this barrier; SMAXPV buf differs from concurrent write buf
// by 2 mod 3. QK || softmax overlap preserved. LDS 40->56 KB (2/CU ok).
// Cheap defer-max gate + setprio (round 9, verified) kept.
// ---------------------------------------------------------------------------
#define BAR_SYNC() do {                                                      \
    asm volatile("s_waitcnt lgkmcnt(0)" ::: "memory");                       \
    __builtin_amdgcn_s_barrier();                                            \
    __builtin_amdgcn_sched_barrier(0);                                       \
  } while (0)

#define ISSUE(KT) do { const size_t ko_ = (size_t)((KT) << 6) * D_;          \
    kr0 = *(const s16x8*)(Kg + ko_);                                         \
    kr1 = *(const s16x8*)(Kg2 + ko_);                                        \
    vr0 = *(const s16x8*)(Vg + ko_);                                         \
    vr1 = *(const s16x8*)(Vg + ko_ + 8);                                     \
  } while (0)

#define WRITEKV(BUFI) do {                                                   \
    bf16* kd_ = Ks[BUFI];                                                    \
    *(s16x8*)&kd_[krow * 64 + (kchunk << 3)] = kr0;                          \
    *(s16x8*)&kd_[(krow + 32) * 64 + (kchunk << 3)] = kr1;                   \
    short* vp_ = (short*)Vt[BUFI];                                           \
    _Pragma("unroll") for (int j = 0; j < 8; ++j) {                          \
      const int d0_ = vd + j, d1_ = vd + 8 + j;                              \
      vp_[d0_ * 64 + (vk ^ ((d0_ & 7) << 3))] = vr0[j];                      \
      vp_[d1_ * 64 + (vk ^ ((d1_ & 7) << 3))] = vr1[j];                      \
    }                                                                        \
  } while (0)

#define QK_LOAD(BUFI) do { const bf16* Kq_ = Ks[BUFI];                       \
    ka0 = *(const s16x8*)&Kq_[( 0 + l15) * 64 + (( 0 + quad * 8) ^ swr)];    \
    ka1 = *(const s16x8*)&Kq_[(16 + l15) * 64 + (( 0 + quad * 8) ^ swr)];    \
    ka2 = *(const s16x8*)&Kq_[(32 + l15) * 64 + (( 0 + quad * 8) ^ swr)];    \
    ka3 = *(const s16x8*)&Kq_[(48 + l15) * 64 + (( 0 + quad * 8) ^ swr)];    \
    kb0 = *(const s16x8*)&Kq_[( 0 + l15) * 64 + ((32 + quad * 8) ^ swr)];    \
    kb1 = *(const s16x8*)&Kq_[(16 + l15) * 64 + ((32 + quad * 8) ^ swr)];    \
    kb2 = *(const s16x8*)&Kq_[(32 + l15) * 64 + ((32 + quad * 8) ^ swr)];    \
    kb3 = *(const s16x8*)&Kq_[(48 + l15) * 64 + ((32 + quad * 8) ^ swr)];    \
  } while (0)

#define QK_MFMA(S0_, S1_, S2_, S3_) do {                                     \
    __builtin_amdgcn_s_setprio(1);                                           \
    f32x4 z_ = {};                                                           \
    z_ = mfma_bf16(qf0, ka0, z_); S0_ = mfma_bf16(qf1, kb0, z_);             \
    z_ = (f32x4){};                                                          \
    z_ = mfma_bf16(qf0, ka1, z_); S1_ = mfma_bf16(qf1, kb1, z_);             \
    z_ = (f32x4){};                                                          \
    z_ = mfma_bf16(qf0, ka2, z_); S2_ = mfma_bf16(qf1, kb2, z_);             \
    z_ = (f32x4){};                                                          \
    z_ = mfma_bf16(qf0, ka3, z_); S3_ = mfma_bf16(qf1, kb3, z_);             \
    __builtin_amdgcn_s_setprio(0);                                           \
  } while (0)

#define SMAXPV(J, BUFI, S0_, S1_, S2_, S3_) do {                             \
    if ((J) == nt - 1) {  /* diagonal tile only */                           \
      _Pragma("unroll") for (int reg = 0; reg < 4; ++reg) {                  \
        const int qrow_ = qb + (w << 4) + quad * 4 + reg;                    \
        const int k0_ = ((J) << 6) + l15;                                    \
        if (k0_ +  0 > qrow_) S0_[reg] = -1e30f;                             \
        if (k0_ + 16 > qrow_) S1_[reg] = -1e30f;                             \
        if (k0_ + 32 > qrow_) S2_[reg] = -1e30f;                             \
        if (k0_ + 48 > qrow_) S3_[reg] = -1e30f;                             \
      }                                                                      \
    }                                                                        \
    float lm_[4];  /* lane-local max only (cheap defer-max gate) */          \
    _Pragma("unroll") for (int reg = 0; reg < 4; ++reg)                      \
      lm_[reg] = fmaxf(fmaxf(S0_[reg], S1_[reg]), fmaxf(S2_[reg], S3_[reg]));\
    bool up_ = false;                                                        \
    _Pragma("unroll") for (int reg = 0; reg < 4; ++reg)                      \
      up_ = up_ || (lm_[reg] > m_i[reg] + 8.f);                              \
    if (__any(up_)) {  /* rare: full reduce + rescale (T13) */               \
      float mx_[4];                                                          \
      _Pragma("unroll") for (int reg = 0; reg < 4; ++reg) mx_[reg] = lm_[reg];\
      _Pragma("unroll") for (int off = 1; off < 16; off <<= 1)               \
        _Pragma("unroll") for (int reg = 0; reg < 4; ++reg)                  \
          mx_[reg] = fmaxf(mx_[reg], __shfl_xor(mx_[reg], off, 64));         \
      _Pragma("unroll") for (int reg = 0; reg < 4; ++reg) {                  \
        const float nm_ = fmaxf(m_i[reg], mx_[reg]);                         \
        const float al_ = __expf(m_i[reg] - nm_);                            \
        m_i[reg] = nm_; l_p[reg] *= al_;                                     \
        o[0][reg] *= al_; o[1][reg] *= al_;                                  \
        o[2][reg] *= al_; o[3][reg] *= al_;                                  \
      }                                                                      \
    }                                                                        \
    _Pragma("unroll") for (int reg = 0; reg < 4; ++reg) {                    \
      const float e0_ = __expf(S0_[reg] - m_i[reg]);                         \
      const float e1_ = __expf(S1_[reg] - m_i[reg]);                         \
      const float e2_ = __expf(S2_[reg] - m_i[reg]);                         \
      const float e3_ = __expf(S3_[reg] - m_i[reg]);                         \
      l_p[reg] += e0_ + e1_ + e2_ + e3_;                                     \
      const int row_ = quad * 4 + reg;                                       \
      bf16* pr_ = &Ps[w][row_ * 64];                                         \
      const int sx_ = (row_ & 7) << 3;                                       \
      pr_[( 0 + l15) ^ sx_] = __float2bfloat16(e0_);                         \
      pr_[(16 + l15) ^ sx_] = __float2bfloat16(e1_);                         \
      pr_[(32 + l15) ^ sx_] = __float2bfloat16(e2_);                         \
      pr_[(48 + l15) ^ sx_] = __float2bfloat16(e3_);                         \
    }                                                                        \
    {                                                                        \
      const bf16* Vc_ = Vt[BUFI];                                            \
      _Pragma("unroll") for (int ks = 0; ks < 2; ++ks) {                     \
        const s16x8 pf_ =                                                    \
            *(const s16x8*)&Ps[w][l15 * 64 + ((ks * 32 + quad * 8) ^ swr)];  \
        __builtin_amdgcn_s_setprio(1);                                       \
        _Pragma("unroll") for (int ni = 0; ni < 4; ++ni) {                   \
          const s16x8 vf_ = *(const s16x8*)                                  \
              &Vc_[(ni * 16 + l15) * 64 + ((ks * 32 + quad * 8) ^ swr)];     \
          o[ni] = mfma_bf16(pf_, vf_, o[ni]);                                \
        }                                                                    \
        __builtin_amdgcn_s_setprio(0);                                       \
      }                                                                      \
    }                                                                        \
  } while (0)

// One barrier per tile; 3-buffer rotation handled by bq/bw/bvb variables.
#define BODY(KT, SO0, SO1, SO2, SO3, SN0, SN1, SN2, SN3) do {                \
    BAR_SYNC();                                                              \
    if ((KT) + 1 < nt) ISSUE((KT) + 1);                                      \
    QK_LOAD(bq);                                                             \
    QK_MFMA(SN0, SN1, SN2, SN3);                                             \
    SMAXPV((KT) - 1, bvb, SO0, SO1, SO2, SO3);                               \
    if ((KT) + 1 < nt) WRITEKV(bw);                                          \
    bvb = bq; bq = bw; bw = (bw == 2) ? 0 : bw + 1;                          \
  } while (0)

__global__ __launch_bounds__(256, 2) void flash_attn(
    const bf16* __restrict__ Q, const bf16* __restrict__ Kk,
    const bf16* __restrict__ V, bf16* __restrict__ O) {
  // XCD-locality decode: all 16 pair-blocks of one (h,b) -> same XCD.
  const int lin = (int)(blockIdx.x + 16 * blockIdx.y + 256 * blockIdx.z);
  const int xcd = lin & 7;
  const int slot = lin >> 3;                  // 0..63
  const int bxp = slot >> 2;                  // 0..15: q-tile pair id
  const int g = xcd + ((slot & 3) << 3);      // 0..31: (h,b) group
  const int h = g & 15, b = g >> 4;

  const int t = threadIdx.x, w = t >> 6, l = t & 63;
  const int l15 = l & 15, quad = l >> 4;
  __shared__ __align__(16) bf16 Ks[3][64 * 64];    // [buf][key][d] swizzled
  __shared__ __align__(16) bf16 Vt[3][64 * 64];    // [buf][d][key] swizzled
  __shared__ __align__(16) bf16 Ps[4][16 * 64];    // per-wave P, swizzled

  // K staging: linear global chunk; swizzle applied at ds_write dest.
  const int krow = t >> 3;                    // 0..31
  const int kchunk = (t & 7) ^ (krow & 7);    // swizzled LDS chunk
  const bf16* Kg  = Kk + (size_t)(b * S_ + krow) * D_ + h * HD_ + ((t & 7) << 3);
  const bf16* Kg2 = Kg + (size_t)32 * D_;
  const int vk = t & 63, vd = w << 4;
  const bf16* Vg = V + (size_t)(b * S_ + vk) * D_ + h * HD_ + vd;
  const int swr = (l15 & 7) << 3;             // read-side xor (elements)

  s16x8 kr0, kr1, vr0, vr1;                   // staging regs (1 tile)
  s16x8 ka0, ka1, ka2, ka3, kb0, kb1, kb2, kb3;  // K fragment regs

#pragma unroll 1
  for (int ph = 0; ph < 2; ++ph) {
    const int qt = ph ? (S_ / 64 - 1 - bxp) : bxp;
    const int qb = qt << 6;
    const int nt = qt + 1;

    __syncthreads();   // protect LDS reuse across phases

    const bf16* qp =
        Q + (size_t)(b * S_ + qb + (w << 4) + l15) * D_ + h * HD_ + quad * 8;
    const s16x8 qf0 = *(const s16x8*)qp;
    const s16x8 qf1 = *(const s16x8*)(qp + 32);

    f32x4 o[4] = {};
    float m_i[4], l_p[4];
#pragma unroll
    for (int r = 0; r < 4; ++r) { m_i[r] = -1e30f; l_p[r] = 0.f; }

    f32x4 sA0, sA1, sA2, sA3, sB0, sB1, sB2, sB3;
    int bq = 1, bw = 2, bvb = 0;   // buf(KT)%3 rotation state (for KT=1)

    // ---- prologue: tile 0 ----
    ISSUE(0);
    WRITEKV(0);                  // counted vmcnt waits for kr/vr (cold, once)
    BAR_SYNC();
    if (nt > 1) ISSUE(1);
    QK_LOAD(0);
    QK_MFMA(sA0, sA1, sA2, sA3);
    if (nt > 1) WRITEKV(1);

    // ---- main loop: 1 barrier/tile, ping-pong score regs ----
    int kt = 1;
    for (; kt + 1 < nt; kt += 2) {
      BODY(kt,     sA0, sA1, sA2, sA3, sB0, sB1, sB2, sB3);
      BODY(kt + 1, sB0, sB1, sB2, sB3, sA0, sA1, sA2, sA3);
    }
    if (kt < nt) {
      BODY(kt, sA0, sA1, sA2, sA3, sB0, sB1, sB2, sB3);
      SMAXPV(nt - 1, bvb, sB0, sB1, sB2, sB3);
    } else {
      SMAXPV(nt - 1, bvb, sA0, sA1, sA2, sA3);
    }

    // ---- epilogue: deferred l reduction + O write ----
    float inv[4];
#pragma unroll
    for (int off = 1; off < 16; off <<= 1)
#pragma unroll
      for (int reg = 0; reg < 4; ++reg)
        l_p[reg] += __shfl_xor(l_p[reg], off, 64);
#pragma unroll
    for (int reg = 0; reg < 4; ++reg) inv[reg] = 1.f / l_p[reg];

#pragma unroll
    for (int reg = 0; reg < 4; ++reg) {
      const int row = b * S_ + qb + (w << 4) + quad * 4 + reg;
      bf16* op = O + (size_t)row * D_ + h * HD_ + l15;
#pragma unroll
      for (int ni = 0; ni < 4; ++ni)
        op[ni * 16] = __float2bfloat16(o[ni][reg] * inv[reg]);
    }
  }
}

// ---------------------------------------------------------------------------
// LN1 (MODE 0): h1 = LN(x_f32 + y1_bf16) -> bf16.
// LN2 (MODE 1): out = LN(X + PA/PB partial) -> fp32 in place.
// One block per 1024-col row.
// ---------------------------------------------------------------------------
template <int MODE>   // 0: LN1, 1: LN2
__global__ __launch_bounds__(256) void add_ln(
    const float* __restrict__ X, const bf16* __restrict__ Y,
    const float* __restrict__ PA, const float* __restrict__ PB,
    const float* __restrict__ g, const float* __restrict__ be,
    void* Out) {
  const int row = blockIdx.x, t = threadIdx.x;
  const size_t base = (size_t)row * D_ + t * 4;
  const float* P = (MODE == 1)
      ? ((row < 2048) ? PA + base : PB + (base - (size_t)2048 * D_))
      : nullptr;
  float v[4];
  float s = 0.f, q = 0.f;
#pragma unroll
  for (int i = 0; i < 4; ++i) {
    v[i] = X[base + i];
    if (MODE == 0) v[i] += b2f(*(const short*)&Y[base + i]);
    else           v[i] += P[i];
    s += v[i];
    q += v[i] * v[i];
  }
#pragma unroll
  for (int off = 32; off; off >>= 1) {
    s += __shfl_down(s, off, 64);
    q += __shfl_down(q, off, 64);
  }
  __shared__ float rs[4], rq[4];
  const int w = t >> 6, l = t & 63;
  if (l == 0) { rs[w] = s; rq[w] = q; }
  __syncthreads();
  s = rs[0] + rs[1] + rs[2] + rs[3];
  q = rq[0] + rq[1] + rq[2] + rq[3];
  const float mu = s * (1.f / D_);
  const float var = q * (1.f / D_) - mu * mu;
  const float rstd = rsqrtf(var + 1e-5f);
#pragma unroll
  for (int i = 0; i < 4; ++i) {
    const float r = (v[i] - mu) * rstd * g[t * 4 + i] + be[t * 4 + i];
    if (MODE == 0) ((bf16*)Out)[base + i] = __float2bfloat16(r);
    else           ((float*)Out)[base + i] = r;
  }
}

extern "C" void kernel_launch(void* const* d_in, const int* in_sizes, int n_in,
                              void* d_out, int out_size, void* d_ws, size_t ws_size,
                              hipStream_t stream) {
  const float* x     = (const float*)d_in[0];
  const float* qkv_b = (const float*)d_in[2];
  const float* out_b = (const float*)d_in[4];
  const float* b1    = (const float*)d_in[6];
  const float* b2    = (const float*)d_in[8];
  const float* l1w   = (const float*)d_in[9];
  const float* l1b   = (const float*)d_in[10];
  const float* l2w   = (const float*)d_in[11];
  const float* l2b   = (const float*)d_in[12];

  float* out    = (float*)d_out;
  float* kcache = out + (size_t)M_ * D_;
  float* vcache = kcache + (size_t)M_ * D_;

  // ws (bf16 elems). High-water 36M elems = 72 MB (<75 MB established safe).
  //  [0,4M)   xc      -> attnb (after QKV) -> pA fp32 partial (after outproj)
  //  [4,7M)   wqkv    -> h1 (after out-proj; h1 spans [4,8M))
  //  [7,8M)   wout
  //  [8,12M)  w1c
  //  [12,16M) w2c
  //  [16,20M) qbuf    -> y1 (after flash) -> pB fp32 partial (after ln1)
  //  [20,24M) kb      -> ffb (after flash; full ffb spans [20,36M))
  //  [24,28M) vb
  bf16* ws    = (bf16*)d_ws;
  bf16* xc    = ws;
  bf16* attnb = ws;
  bf16* wqkv  = ws + 4 * MEG;
  bf16* h1    = ws + 4 * MEG;
  bf16* wout  = ws + 7 * MEG;
  bf16* w1c   = ws + 8 * MEG;
  bf16* w2c   = ws + 12 * MEG;
  bf16* qbuf  = ws + 16 * MEG;
  bf16* y1    = ws + 16 * MEG;
  bf16* kb    = ws + 20 * MEG;
  bf16* ffb   = ws + 20 * MEG;
  bf16* vb    = ws + 24 * MEG;
  float* pA   = (float*)ws;               // rows 0..2047  K-half-1 partial
  float* pB   = (float*)(ws + 16 * MEG);  // rows 2048..4095

  const dim3 blk(256);

  // all 5 fp32->bf16 conversions in one dispatch
  CvtArgs ca;
  ca.src[0] = x;                    ca.dst[0] = xc;   ca.n[0] = M_ * D_;
  ca.src[1] = (const float*)d_in[1]; ca.dst[1] = wqkv; ca.n[1] = 3 * D_ * D_;
  ca.src[2] = (const float*)d_in[3]; ca.dst[2] = wout; ca.n[2] = D_ * D_;
  ca.src[3] = (const float*)d_in[5]; ca.dst[3] = w1c;  ca.n[3] = FFD_ * D_;
  ca.src[4] = (const float*)d_in[7]; ca.dst[4] = w2c;  ca.n[4] = D_ * FFD_;
  cvt_f2b_multi<<<dim3((M_ * D_ + 2047) / 2048, 5), blk, 0, stream>>>(ca);

  // QKV: q (pre-scaled 0.125) -> qbuf bf16; k/v->fp32 caches + bf16 ws copies.
  gemm_bt<3><<<dim3(3 * D_ / 128, M_ / 128), blk, 0, stream>>>(
      xc, wqkv, qkv_b, qbuf, nullptr, kcache, kb, vcache, vb, nullptr,
      M_, 3 * D_, D_);
  flash_attn<<<dim3(S_ / 128, H_, B_), blk, 0, stream>>>(qbuf, kb, vb, attnb);
  // out-proj -> y1 bf16 (overwrites dead qbuf)
  gemm_bt<0><<<dim3(D_ / 128, M_ / 128), blk, 0, stream>>>(
      attnb, wout, out_b, y1, nullptr, nullptr, nullptr, nullptr, nullptr,
      nullptr, M_, D_, D_);
  // h1 = LN(x + y1) -> bf16 (overwrites dead wqkv)
  add_ln<0><<<dim3(M_), blk, 0, stream>>>(x, y1, nullptr, nullptr, l1w, l1b, h1);
  // MLP full-M: MLP1 -> ffb [20,36M); MLP2 split-K=2 + BK=64:
  // z=0 K-half-0 + bias + resid -> out; z=1 K-half-1 raw -> pA/pB.
  gemm_bt<1><<<dim3(FFD_ / 128, M_ / 128), blk, 0, stream>>>(
      h1, w1c, b1, ffb, nullptr, nullptr, nullptr, nullptr, nullptr,
      nullptr, M_, FFD_, D_);
  gemm_bt<2><<<dim3(D_ / 128, M_ / 128, 2), blk, 0, stream>>>(
      ffb, w2c, b2, nullptr, out, pA, nullptr, pB, nullptr,
      h1, M_, D_, FFD_);
  // out = LN(out + partial) in place, fp32.
  add_ln<1><<<dim3(M_), blk, 0, stream>>>(out, nullptr, pA, pB, l2w, l2b, out);
}

// Round 11
// 358.576 us; speedup vs baseline: 1.0884x; 1.0027x over previous
//
#include <hip/hip_runtime.h>
#include <hip/hip_bf16.h>
#include <stdint.h>

typedef __hip_bfloat16 bf16;
typedef __attribute__((ext_vector_type(8))) short s16x8;
typedef __attribute__((ext_vector_type(4))) float f32x4;

#define B_   2
#define S_   2048
#define D_   1024
#define H_   16
#define HD_  64
#define FFD_ 4096
#define M_   4096
#define MEG  ((size_t)1048576)

__device__ __forceinline__ f32x4 mfma_bf16(s16x8 a, s16x8 b, f32x4 c) {
  return __builtin_amdgcn_mfma_f32_16x16x32_bf16(a, b, c, 0, 0, 0);
}

__device__ __forceinline__ void gl_lds16(const bf16* g, bf16* l) {
  __builtin_amdgcn_global_load_lds(
      (const __attribute__((address_space(1))) void*)g,
      (__attribute__((address_space(3))) void*)l, 16, 0, 0);
}

__device__ __forceinline__ float b2f(short u) {
  union { uint32_t i; float f; } z;
  z.i = ((uint32_t)(unsigned short)u) << 16;
  return z.f;
}
__device__ __forceinline__ short f2b(float f) {
  const bf16 h = __float2bfloat16(f);
  return *(const short*)&h;
}

// ---------------------------------------------------------------------------
// fp32 -> bf16 conversion, all 5 tensors in ONE dispatch (z-indexed).
// ---------------------------------------------------------------------------
struct CvtArgs {
  const float* src[5];
  bf16* dst[5];
  int n[5];
};
__global__ __launch_bounds__(256) void cvt_f2b_multi(CvtArgs a) {
  const int z = blockIdx.y;
  const int idx = (blockIdx.x * 256 + threadIdx.x) * 8;
  if (idx >= a.n[z]) return;
  const float* src = a.src[z];
  s16x8 o;
#pragma unroll
  for (int i = 0; i < 8; ++i) o[i] = f2b(src[idx + i]);
  *(s16x8*)(a.dst[z] + idx) = o;
}

// ---------------------------------------------------------------------------
// MFMA NT GEMM: C[m,n] = sum_k A[m,k]*W[n,k] + bias[n]  (bias fp32)
// 128x128 tile, 4 waves (2x2), 4x4 16x16x32 frags.
// v7: 2-buffer gl_lds, one __syncthreads drain per K-step (round-5 v2,
//     verified fastest); 1D T1 XCD chunk for ALL modes (round-10 2D chunk
//     cut FETCH 69.8->41 MB but cost +9 us — not fetch-bound; reverted).
//     BK=64 for MODE 0/2/4 (occupancy slack); chunk-XOR swizzle on BK=64.
// MODE 0: (unused)
// MODE 1: relu, C -> bf16 Cb       (MLP1 -> ff)               [BK=32]
// MODE 2: SPLIT-K=2. z=0: K-half-0 + bias + resid -> fp32 Cf;
//         z=1: raw -> fp32 Kf (rows<2048) / Vf (rows>=2048).  [BK=64]
// MODE 3: QKV split: seg0 q*0.125 -> bf16 Cb; seg1 k->fp32 Kf + bf16 Kb;
//         seg2 v->fp32 Vf + bf16 Vb.                          [BK=32]
// MODE 4: out-proj SPLIT-K=2 (1 blk/CU -> 2): z=0: K-half-0 + bias -> Cf;
//         z=1: raw K-half-1 -> Kf. LN1 sums Cf+Kf.            [BK=64]
// ---------------------------------------------------------------------------
template <int MODE>
__global__ __launch_bounds__(256) void gemm_bt(
    const bf16* __restrict__ A, const bf16* __restrict__ W,
    const float* __restrict__ bias,
    bf16* __restrict__ Cb, float* __restrict__ Cf,
    float* __restrict__ Kf, bf16* __restrict__ Kb,
    float* __restrict__ Vf, bf16* __restrict__ Vb,
    const bf16* __restrict__ Res,
    int M, int N, int K) {
  constexpr int BK = (MODE == 2 || MODE == 0 || MODE == 4) ? 64 : 32;
  constexpr bool SPLITK = (MODE == 2 || MODE == 4);
  __shared__ __align__(16) bf16 As[2][128 * BK];
  __shared__ __align__(16) bf16 Bs[2][128 * BK];
  const int t = threadIdx.x;

  // 1D T1 XCD-chunked swizzle (nwg % 8 == 0 -> bijective).
  const int bid = blockIdx.y * gridDim.x + blockIdx.x;
  const int nwg = gridDim.x * gridDim.y;
  const int sw  = (bid & 7) * (nwg >> 3) + (bid >> 3);
  const int m0 = (sw / gridDim.x) << 7, n0 = (sw % gridDim.x) << 7;

  const int w = t >> 6, l = t & 63;
  const int wm = (w >> 1) << 6, wn = (w & 1) << 6;
  const int l15 = l & 15, quad = l >> 4;

  const int kz   = SPLITK ? (int)blockIdx.z : 0;   // K-split index
  const int Keff = SPLITK ? (K >> 1) : K;

  f32x4 acc[4][4] = {};

  // staging addresses
  const int srow = (BK == 32) ? (t >> 2) : (t >> 3);
  const int scol = (BK == 32) ? ((t & 3) << 3)
                              : (((t & 7) ^ ((t >> 3) & 7)) << 3);  // pre-swz
  const bf16* Ag  = A + (size_t)(m0 + srow) * K + kz * Keff + scol;
  const bf16* Ag2 = Ag + ((size_t)K << 6);   // +64 rows (BK=32 path)
  const bf16* Wg  = W + (size_t)(n0 + srow) * K + kz * Keff + scol;
  const bf16* Wg2 = Wg + ((size_t)K << 6);

#define STAGE_G(KI, BUF) do {                                                \
    if constexpr (BK == 32) {                                                \
      const int ko_ = (KI) * 32;                                             \
      gl_lds16(Ag + ko_, (bf16*)As[BUF] + t * 8);                            \
      gl_lds16(Ag2 + ko_, (bf16*)As[BUF] + 2048 + t * 8);                    \
      gl_lds16(Wg + ko_, (bf16*)Bs[BUF] + t * 8);                            \
      gl_lds16(Wg2 + ko_, (bf16*)Bs[BUF] + 2048 + t * 8);                    \
    } else {                                                                 \
      const int ko_ = (KI) * 64;                                             \
      _Pragma("unroll") for (int i_ = 0; i_ < 4; ++i_) {                     \
        gl_lds16(Ag + ko_ + (size_t)32 * K * i_,                             \
                 (bf16*)As[BUF] + i_ * 2048 + t * 8);                        \
        gl_lds16(Wg + ko_ + (size_t)32 * K * i_,                             \
                 (bf16*)Bs[BUF] + i_ * 2048 + t * 8);                        \
      }                                                                      \
    }                                                                        \
  } while (0)

  const int nk = Keff / BK;
  STAGE_G(0, 0);
  __syncthreads();

  for (int ki = 0; ki < nk; ++ki) {
    const int cur = ki & 1;
    if (ki + 1 < nk) STAGE_G(ki + 1, cur ^ 1);

    const s16x8* As8 = (const s16x8*)As[cur];
    const s16x8* Bs8 = (const s16x8*)Bs[cur];
    if constexpr (BK == 32) {
      s16x8 af[4], bfr[4];
#pragma unroll
      for (int i = 0; i < 4; ++i) af[i]  = As8[((wm + i * 16 + l15) << 2) + quad];
#pragma unroll
      for (int i = 0; i < 4; ++i) bfr[i] = Bs8[((wn + i * 16 + l15) << 2) + quad];
      __builtin_amdgcn_s_setprio(1);
#pragma unroll
      for (int mi = 0; mi < 4; ++mi)
#pragma unroll
        for (int ni = 0; ni < 4; ++ni)
          acc[mi][ni] = mfma_bf16(af[mi], bfr[ni], acc[mi][ni]);
      __builtin_amdgcn_s_setprio(0);
    } else {
      const int sx = l15 & 7;
#pragma unroll
      for (int h = 0; h < 2; ++h) {
        s16x8 af[4], bfr[4];
#pragma unroll
        for (int i = 0; i < 4; ++i)
          af[i]  = As8[((wm + i * 16 + l15) << 3) + ((h * 4 + quad) ^ sx)];
#pragma unroll
        for (int i = 0; i < 4; ++i)
          bfr[i] = Bs8[((wn + i * 16 + l15) << 3) + ((h * 4 + quad) ^ sx)];
        __builtin_amdgcn_s_setprio(1);
#pragma unroll
        for (int mi = 0; mi < 4; ++mi)
#pragma unroll
          for (int ni = 0; ni < 4; ++ni)
            acc[mi][ni] = mfma_bf16(af[mi], bfr[ni], acc[mi][ni]);
        __builtin_amdgcn_s_setprio(0);
      }
    }
    __syncthreads();
  }
#undef STAGE_G

  float bv[4];
#pragma unroll
  for (int ni = 0; ni < 4; ++ni)
    bv[ni] = bias[n0 + wn + ni * 16 + l15];

  const int seg = n0 >> 10, nb2 = n0 & 1023;
#pragma unroll
  for (int mi = 0; mi < 4; ++mi) {
#pragma unroll
    for (int reg = 0; reg < 4; ++reg) {
      const int row = m0 + wm + mi * 16 + quad * 4 + reg;
#pragma unroll
      for (int ni = 0; ni < 4; ++ni) {
        float v = acc[mi][ni][reg] + ((SPLITK && kz) ? 0.f : bv[ni]);
        if (MODE == 1) {
          v = fmaxf(v, 0.f);
          Cb[(size_t)row * N + n0 + wn + ni * 16 + l15] = __float2bfloat16(v);
        } else if (MODE == 2) {
          const size_t col = n0 + wn + ni * 16 + l15;
          if (kz == 0) {
            const size_t o = (size_t)row * N + col;
            Cf[o] = v + b2f(*(const short*)&Res[o]);
          } else {
            float* P = (row < 2048) ? Kf : Vf;   // partial bufs (dead ws)
            P[(size_t)(row & 2047) * N + col] = v;
          }
        } else if (MODE == 4) {
          const size_t o = (size_t)row * N + n0 + wn + ni * 16 + l15;
          if (kz == 0) Cf[o] = v;            // bias + K-half-0
          else         Kf[o] = v;            // raw K-half-1
        } else {  // MODE 3
          const size_t o = (size_t)row * 1024 + nb2 + wn + ni * 16 + l15;
          if (seg == 0) {
            Cb[o] = __float2bfloat16(v * 0.125f);   // pre-scale Q by 1/sqrt(hd)
          } else if (seg == 1) {
            Kf[o] = v; Kb[o] = __float2bfloat16(v);
          } else {
            Vf[o] = v; Vb[o] = __float2bfloat16(v);
          }
        }
      }
    }
  }
}

// ---------------------------------------------------------------------------
// MFMA flash attention v7, causal, hd=64.  (unchanged from round 10)
// 3-buffer K/V, single barrier per tile; XCD-locality decode; cheap
// defer-max gate; setprio. Verified: FETCH 12.4 MB, ~44 us.
// ---------------------------------------------------------------------------
#define BAR_SYNC() do {                                                      \
    asm volatile("s_waitcnt lgkmcnt(0)" ::: "memory");                       \
    __builtin_amdgcn_s_barrier();                                            \
    __builtin_amdgcn_sched_barrier(0);                                       \
  } while (0)

#define ISSUE(KT) do { const size_t ko_ = (size_t)((KT) << 6) * D_;          \
    kr0 = *(const s16x8*)(Kg + ko_);                                         \
    kr1 = *(const s16x8*)(Kg2 + ko_);                                        \
    vr0 = *(const s16x8*)(Vg + ko_);                                         \
    vr1 = *(const s16x8*)(Vg + ko_ + 8);                                     \
  } while (0)

#define WRITEKV(BUFI) do {                                                   \
    bf16* kd_ = Ks[BUFI];                                                    \
    *(s16x8*)&kd_[krow * 64 + (kchunk << 3)] = kr0;                          \
    *(s16x8*)&kd_[(krow + 32) * 64 + (kchunk << 3)] = kr1;                   \
    short* vp_ = (short*)Vt[BUFI];                                           \
    _Pragma("unroll") for (int j = 0; j < 8; ++j) {                          \
      const int d0_ = vd + j, d1_ = vd + 8 + j;                              \
      vp_[d0_ * 64 + (vk ^ ((d0_ & 7) << 3))] = vr0[j];                      \
      vp_[d1_ * 64 + (vk ^ ((d1_ & 7) << 3))] = vr1[j];                      \
    }                                                                        \
  } while (0)

#define QK_LOAD(BUFI) do { const bf16* Kq_ = Ks[BUFI];                       \
    ka0 = *(const s16x8*)&Kq_[( 0 + l15) * 64 + (( 0 + quad * 8) ^ swr)];    \
    ka1 = *(const s16x8*)&Kq_[(16 + l15) * 64 + (( 0 + quad * 8) ^ swr)];    \
    ka2 = *(const s16x8*)&Kq_[(32 + l15) * 64 + (( 0 + quad * 8) ^ swr)];    \
    ka3 = *(const s16x8*)&Kq_[(48 + l15) * 64 + (( 0 + quad * 8) ^ swr)];    \
    kb0 = *(const s16x8*)&Kq_[( 0 + l15) * 64 + ((32 + quad * 8) ^ swr)];    \
    kb1 = *(const s16x8*)&Kq_[(16 + l15) * 64 + ((32 + quad * 8) ^ swr)];    \
    kb2 = *(const s16x8*)&Kq_[(32 + l15) * 64 + ((32 + quad * 8) ^ swr)];    \
    kb3 = *(const s16x8*)&Kq_[(48 + l15) * 64 + ((32 + quad * 8) ^ swr)];    \
  } while (0)

#define QK_MFMA(S0_, S1_, S2_, S3_) do {                                     \
    __builtin_amdgcn_s_setprio(1);                                           \
    f32x4 z_ = {};                                                           \
    z_ = mfma_bf16(qf0, ka0, z_); S0_ = mfma_bf16(qf1, kb0, z_);             \
    z_ = (f32x4){};                                                          \
    z_ = mfma_bf16(qf0, ka1, z_); S1_ = mfma_bf16(qf1, kb1, z_);             \
    z_ = (f32x4){};                                                          \
    z_ = mfma_bf16(qf0, ka2, z_); S2_ = mfma_bf16(qf1, kb2, z_);             \
    z_ = (f32x4){};                                                          \
    z_ = mfma_bf16(qf0, ka3, z_); S3_ = mfma_bf16(qf1, kb3, z_);             \
    __builtin_amdgcn_s_setprio(0);                                           \
  } while (0)

#define SMAXPV(J, BUFI, S0_, S1_, S2_, S3_) do {                             \
    if ((J) == nt - 1) {  /* diagonal tile only */                           \
      _Pragma("unroll") for (int reg = 0; reg < 4; ++reg) {                  \
        const int qrow_ = qb + (w << 4) + quad * 4 + reg;                    \
        const int k0_ = ((J) << 6) + l15;                                    \
        if (k0_ +  0 > qrow_) S0_[reg] = -1e30f;                             \
        if (k0_ + 16 > qrow_) S1_[reg] = -1e30f;                             \
        if (k0_ + 32 > qrow_) S2_[reg] = -1e30f;                             \
        if (k0_ + 48 > qrow_) S3_[reg] = -1e30f;                             \
      }                                                                      \
    }                                                                        \
    float lm_[4];  /* lane-local max only (cheap defer-max gate) */          \
    _Pragma("unroll") for (int reg = 0; reg < 4; ++reg)                      \
      lm_[reg] = fmaxf(fmaxf(S0_[reg], S1_[reg]), fmaxf(S2_[reg], S3_[reg]));\
    bool up_ = false;                                                        \
    _Pragma("unroll") for (int reg = 0; reg < 4; ++reg)                      \
      up_ = up_ || (lm_[reg] > m_i[reg] + 8.f);                              \
    if (__any(up_)) {  /* rare: full reduce + rescale (T13) */               \
      float mx_[4];                                                          \
      _Pragma("unroll") for (int reg = 0; reg < 4; ++reg) mx_[reg] = lm_[reg];\
      _Pragma("unroll") for (int off = 1; off < 16; off <<= 1)               \
        _Pragma("unroll") for (int reg = 0; reg < 4; ++reg)                  \
          mx_[reg] = fmaxf(mx_[reg], __shfl_xor(mx_[reg], off, 64));         \
      _Pragma("unroll") for (int reg = 0; reg < 4; ++reg) {                  \
        const float nm_ = fmaxf(m_i[reg], mx_[reg]);                         \
        const float al_ = __expf(m_i[reg] - nm_);                            \
        m_i[reg] = nm_; l_p[reg] *= al_;                                     \
        o[0][reg] *= al_; o[1][reg] *= al_;                                  \
        o[2][reg] *= al_; o[3][reg] *= al_;                                  \
      }                                                                      \
    }                                                                        \
    _Pragma("unroll") for (int reg = 0; reg < 4; ++reg) {                    \
      const float e0_ = __expf(S0_[reg] - m_i[reg]);                         \
      const float e1_ = __expf(S1_[reg] - m_i[reg]);                         \
      const float e2_ = __expf(S2_[reg] - m_i[reg]);                         \
      const float e3_ = __expf(S3_[reg] - m_i[reg]);                         \
      l_p[reg] += e0_ + e1_ + e2_ + e3_;                                     \
      const int row_ = quad * 4 + reg;                                       \
      bf16* pr_ = &Ps[w][row_ * 64];                                         \
      const int sx_ = (row_ & 7) << 3;                                       \
      pr_[( 0 + l15) ^ sx_] = __float2bfloat16(e0_);                         \
      pr_[(16 + l15) ^ sx_] = __float2bfloat16(e1_);                         \
      pr_[(32 + l15) ^ sx_] = __float2bfloat16(e2_);                         \
      pr_[(48 + l15) ^ sx_] = __float2bfloat16(e3_);                         \
    }                                                                        \
    {                                                                        \
      const bf16* Vc_ = Vt[BUFI];                                            \
      _Pragma("unroll") for (int ks = 0; ks < 2; ++ks) {                     \
        const s16x8 pf_ =                                                    \
            *(const s16x8*)&Ps[w][l15 * 64 + ((ks * 32 + quad * 8) ^ swr)];  \
        __builtin_amdgcn_s_setprio(1);                                       \
        _Pragma("unroll") for (int ni = 0; ni < 4; ++ni) {                   \
          const s16x8 vf_ = *(const s16x8*)                                  \
              &Vc_[(ni * 16 + l15) * 64 + ((ks * 32 + quad * 8) ^ swr)];     \
          o[ni] = mfma_bf16(pf_, vf_, o[ni]);                                \
        }                                                                    \
        __builtin_amdgcn_s_setprio(0);                                       \
      }                                                                      \
    }                                                                        \
  } while (0)

// One barrier per tile; 3-buffer rotation handled by bq/bw/bvb variables.
#define BODY(KT, SO0, SO1, SO2, SO3, SN0, SN1, SN2, SN3) do {                \
    BAR_SYNC();                                                              \
    if ((KT) + 1 < nt) ISSUE((KT) + 1);                                      \
    QK_LOAD(bq);                                                             \
    QK_MFMA(SN0, SN1, SN2, SN3);                                             \
    SMAXPV((KT) - 1, bvb, SO0, SO1, SO2, SO3);                               \
    if ((KT) + 1 < nt) WRITEKV(bw);                                          \
    bvb = bq; bq = bw; bw = (bw == 2) ? 0 : bw + 1;                          \
  } while (0)

__global__ __launch_bounds__(256, 2) void flash_attn(
    const bf16* __restrict__ Q, const bf16* __restrict__ Kk,
    const bf16* __restrict__ V, bf16* __restrict__ O) {
  // XCD-locality decode: all 16 pair-blocks of one (h,b) -> same XCD.
  const int lin = (int)(blockIdx.x + 16 * blockIdx.y + 256 * blockIdx.z);
  const int xcd = lin & 7;
  const int slot = lin >> 3;                  // 0..63
  const int bxp = slot >> 2;                  // 0..15: q-tile pair id
  const int g = xcd + ((slot & 3) << 3);      // 0..31: (h,b) group
  const int h = g & 15, b = g >> 4;

  const int t = threadIdx.x, w = t >> 6, l = t & 63;
  const int l15 = l & 15, quad = l >> 4;
  __shared__ __align__(16) bf16 Ks[3][64 * 64];    // [buf][key][d] swizzled
  __shared__ __align__(16) bf16 Vt[3][64 * 64];    // [buf][d][key] swizzled
  __shared__ __align__(16) bf16 Ps[4][16 * 64];    // per-wave P, swizzled

  // K staging: linear global chunk; swizzle applied at ds_write dest.
  const int krow = t >> 3;                    // 0..31
  const int kchunk = (t & 7) ^ (krow & 7);    // swizzled LDS chunk
  const bf16* Kg  = Kk + (size_t)(b * S_ + krow) * D_ + h * HD_ + ((t & 7) << 3);
  const bf16* Kg2 = Kg + (size_t)32 * D_;
  const int vk = t & 63, vd = w << 4;
  const bf16* Vg = V + (size_t)(b * S_ + vk) * D_ + h * HD_ + vd;
  const int swr = (l15 & 7) << 3;             // read-side xor (elements)

  s16x8 kr0, kr1, vr0, vr1;                   // staging regs (1 tile)
  s16x8 ka0, ka1, ka2, ka3, kb0, kb1, kb2, kb3;  // K fragment regs

#pragma unroll 1
  for (int ph = 0; ph < 2; ++ph) {
    const int qt = ph ? (S_ / 64 - 1 - bxp) : bxp;
    const int qb = qt << 6;
    const int nt = qt + 1;

    __syncthreads();   // protect LDS reuse across phases

    const bf16* qp =
        Q + (size_t)(b * S_ + qb + (w << 4) + l15) * D_ + h * HD_ + quad * 8;
    const s16x8 qf0 = *(const s16x8*)qp;
    const s16x8 qf1 = *(const s16x8*)(qp + 32);

    f32x4 o[4] = {};
    float m_i[4], l_p[4];
#pragma unroll
    for (int r = 0; r < 4; ++r) { m_i[r] = -1e30f; l_p[r] = 0.f; }

    f32x4 sA0, sA1, sA2, sA3, sB0, sB1, sB2, sB3;
    int bq = 1, bw = 2, bvb = 0;   // buf(KT)%3 rotation state (for KT=1)

    // ---- prologue: tile 0 ----
    ISSUE(0);
    WRITEKV(0);                  // counted vmcnt waits for kr/vr (cold, once)
    BAR_SYNC();
    if (nt > 1) ISSUE(1);
    QK_LOAD(0);
    QK_MFMA(sA0, sA1, sA2, sA3);
    if (nt > 1) WRITEKV(1);

    // ---- main loop: 1 barrier/tile, ping-pong score regs ----
    int kt = 1;
    for (; kt + 1 < nt; kt += 2) {
      BODY(kt,     sA0, sA1, sA2, sA3, sB0, sB1, sB2, sB3);
      BODY(kt + 1, sB0, sB1, sB2, sB3, sA0, sA1, sA2, sA3);
    }
    if (kt < nt) {
      BODY(kt, sA0, sA1, sA2, sA3, sB0, sB1, sB2, sB3);
      SMAXPV(nt - 1, bvb, sB0, sB1, sB2, sB3);
    } else {
      SMAXPV(nt - 1, bvb, sA0, sA1, sA2, sA3);
    }

    // ---- epilogue: deferred l reduction + O write ----
    float inv[4];
#pragma unroll
    for (int off = 1; off < 16; off <<= 1)
#pragma unroll
      for (int reg = 0; reg < 4; ++reg)
        l_p[reg] += __shfl_xor(l_p[reg], off, 64);
#pragma unroll
    for (int reg = 0; reg < 4; ++reg) inv[reg] = 1.f / l_p[reg];

#pragma unroll
    for (int reg = 0; reg < 4; ++reg) {
      const int row = b * S_ + qb + (w << 4) + quad * 4 + reg;
      bf16* op = O + (size_t)row * D_ + h * HD_ + l15;
#pragma unroll
      for (int ni = 0; ni < 4; ++ni)
        op[ni * 16] = __float2bfloat16(o[ni][reg] * inv[reg]);
    }
  }
}

// ---------------------------------------------------------------------------
// LN1 (MODE 0): h1 = LN(x_f32 + P0 + P1) -> bf16  (P0/P1 = out-proj K-half
//               fp32 partials; P0 carries the bias).
// LN2 (MODE 1): out = LN(X + PA/PB row-split partial) -> fp32 in place.
// One block per 1024-col row.
// ---------------------------------------------------------------------------
template <int MODE>   // 0: LN1, 1: LN2
__global__ __launch_bounds__(256) void add_ln(
    const float* __restrict__ X,
    const float* __restrict__ PA, const float* __restrict__ PB,
    const float* __restrict__ g, const float* __restrict__ be,
    void* Out) {
  const int row = blockIdx.x, t = threadIdx.x;
  const size_t base = (size_t)row * D_ + t * 4;
  const float* P = (MODE == 1)
      ? ((row < 2048) ? PA + base : PB + (base - (size_t)2048 * D_))
      : nullptr;
  float v[4];
  float s = 0.f, q = 0.f;
#pragma unroll
  for (int i = 0; i < 4; ++i) {
    v[i] = X[base + i];
    if (MODE == 0) v[i] += PA[base + i] + PB[base + i];
    else           v[i] += P[i];
    s += v[i];
    q += v[i] * v[i];
  }
#pragma unroll
  for (int off = 32; off; off >>= 1) {
    s += __shfl_down(s, off, 64);
    q += __shfl_down(q, off, 64);
  }
  __shared__ float rs[4], rq[4];
  const int w = t >> 6, l = t & 63;
  if (l == 0) { rs[w] = s; rq[w] = q; }
  __syncthreads();
  s = rs[0] + rs[1] + rs[2] + rs[3];
  q = rq[0] + rq[1] + rq[2] + rq[3];
  const float mu = s * (1.f / D_);
  const float var = q * (1.f / D_) - mu * mu;
  const float rstd = rsqrtf(var + 1e-5f);
#pragma unroll
  for (int i = 0; i < 4; ++i) {
    const float r = (v[i] - mu) * rstd * g[t * 4 + i] + be[t * 4 + i];
    if (MODE == 0) ((bf16*)Out)[base + i] = __float2bfloat16(r);
    else           ((float*)Out)[base + i] = r;
  }
}

extern "C" void kernel_launch(void* const* d_in, const int* in_sizes, int n_in,
                              void* d_out, int out_size, void* d_ws, size_t ws_size,
                              hipStream_t stream) {
  const float* x     = (const float*)d_in[0];
  const float* qkv_b = (const float*)d_in[2];
  const float* out_b = (const float*)d_in[4];
  const float* b1    = (const float*)d_in[6];
  const float* b2    = (const float*)d_in[8];
  const float* l1w   = (const float*)d_in[9];
  const float* l1b   = (const float*)d_in[10];
  const float* l2w   = (const float*)d_in[11];
  const float* l2b   = (const float*)d_in[12];

  float* out    = (float*)d_out;
  float* kcache = out + (size_t)M_ * D_;
  float* vcache = kcache + (size_t)M_ * D_;

  // ws (bf16 elems). High-water 36M elems = 72 MB (<75 MB established safe).
  //  [0,4M)   xc -> attnb (after QKV) -> pA fp32 MLP2 partial (after LN1)
  //  [4,7M)   wqkv -> h1 (after out-proj; h1 spans [4,8M))
  //  [7,8M)   wout
  //  [8,12M)  w1c
  //  [12,16M) w2c
  //  [16,20M) qbuf (dead after flash) -> pB fp32 MLP2 partial
  //  [20,24M) kb;  [24,28M) vb  (dead after flash)
  //  [20,28M) oP0 fp32 out-proj partial 0 (after flash)
  //  [28,36M) oP1 fp32 out-proj partial 1
  //  [20,36M) ffb (after LN1)
  bf16* ws    = (bf16*)d_ws;
  bf16* xc    = ws;
  bf16* attnb = ws;
  bf16* wqkv  = ws + 4 * MEG;
  bf16* h1    = ws + 4 * MEG;
  bf16* wout  = ws + 7 * MEG;
  bf16* w1c   = ws + 8 * MEG;
  bf16* w2c   = ws + 12 * MEG;
  bf16* qbuf  = ws + 16 * MEG;
  bf16* kb    = ws + 20 * MEG;
  bf16* ffb   = ws + 20 * MEG;
  bf16* vb    = ws + 24 * MEG;
  float* oP0  = (float*)(ws + 20 * MEG);  // out-proj K-half-0 + bias
  float* oP1  = (float*)(ws + 28 * MEG);  // out-proj K-half-1 raw
  float* pA   = (float*)ws;               // MLP2 rows 0..2047 partial
  float* pB   = (float*)(ws + 16 * MEG);  // MLP2 rows 2048..4095 partial

  const dim3 blk(256);

  // all 5 fp32->bf16 conversions in one dispatch
  CvtArgs ca;
  ca.src[0] = x;                    ca.dst[0] = xc;   ca.n[0] = M_ * D_;
  ca.src[1] = (const float*)d_in[1]; ca.dst[1] = wqkv; ca.n[1] = 3 * D_ * D_;
  ca.src[2] = (const float*)d_in[3]; ca.dst[2] = wout; ca.n[2] = D_ * D_;
  ca.src[3] = (const float*)d_in[5]; ca.dst[3] = w1c;  ca.n[3] = FFD_ * D_;
  ca.src[4] = (const float*)d_in[7]; ca.dst[4] = w2c;  ca.n[4] = D_ * FFD_;
  cvt_f2b_multi<<<dim3((M_ * D_ + 2047) / 2048, 5), blk, 0, stream>>>(ca);

  // QKV: q (pre-scaled 0.125) -> qbuf bf16; k/v->fp32 caches + bf16 ws copies.
  gemm_bt<3><<<dim3(3 * D_ / 128, M_ / 128), blk, 0, stream>>>(
      xc, wqkv, qkv_b, qbuf, nullptr, kcache, kb, vcache, vb, nullptr,
      M_, 3 * D_, D_);
  flash_attn<<<dim3(S_ / 128, H_, B_), blk, 0, stream>>>(qbuf, kb, vb, attnb);
  // out-proj SPLIT-K=2: z=0 bias + K-half-0 -> oP0; z=1 raw -> oP1.
  gemm_bt<4><<<dim3(D_ / 128, M_ / 128, 2), blk, 0, stream>>>(
      attnb, wout, out_b, nullptr, oP0, oP1, nullptr, nullptr, nullptr,
      nullptr, M_, D_, D_);
  // h1 = LN(x + oP0 + oP1) -> bf16 (overwrites dead wqkv)
  add_ln<0><<<dim3(M_), blk, 0, stream>>>(x, oP0, oP1, l1w, l1b, h1);
  // MLP full-M: MLP1 -> ffb [20,36M); MLP2 split-K=2 + BK=64:
  // z=0 K-half-0 + bias + resid -> out; z=1 K-half-1 raw -> pA/pB.
  gemm_bt<1><<<dim3(FFD_ / 128, M_ / 128), blk, 0, stream>>>(
      h1, w1c, b1, ffb, nullptr, nullptr, nullptr, nullptr, nullptr,
      nullptr, M_, FFD_, D_);
  gemm_bt<2><<<dim3(D_ / 128, M_ / 128, 2), blk, 0, stream>>>(
      ffb, w2c, b2, nullptr, out, pA, nullptr, pB, nullptr,
      h1, M_, D_, FFD_);
  // out = LN(out + partial) in place, fp32.
  add_ln<1><<<dim3(M_), blk, 0, stream>>>(out, pA, pB, l2w, l2b, out);
}

// Round 12
// 355.378 us; speedup vs baseline: 1.0982x; 1.0090x over previous
//
#include <hip/hip_runtime.h>
#include <hip/hip_bf16.h>
#include <stdint.h>

typedef __hip_bfloat16 bf16;
typedef __attribute__((ext_vector_type(8))) short s16x8;
typedef __attribute__((ext_vector_type(4))) float f32x4;

#define B_   2
#define S_   2048
#define D_   1024
#define H_   16
#define HD_  64
#define FFD_ 4096
#define M_   4096
#define MEG  ((size_t)1048576)

__device__ __forceinline__ f32x4 mfma_bf16(s16x8 a, s16x8 b, f32x4 c) {
  return __builtin_amdgcn_mfma_f32_16x16x32_bf16(a, b, c, 0, 0, 0);
}

__device__ __forceinline__ void gl_lds16(const bf16* g, bf16* l) {
  __builtin_amdgcn_global_load_lds(
      (const __attribute__((address_space(1))) void*)g,
      (__attribute__((address_space(3))) void*)l, 16, 0, 0);
}

__device__ __forceinline__ float b2f(short u) {
  union { uint32_t i; float f; } z;
  z.i = ((uint32_t)(unsigned short)u) << 16;
  return z.f;
}
__device__ __forceinline__ short f2b(float f) {
  const bf16 h = __float2bfloat16(f);
  return *(const short*)&h;
}

// ---------------------------------------------------------------------------
// fp32 -> bf16 conversion, all 5 tensors in ONE dispatch (z-indexed).
// ---------------------------------------------------------------------------
struct CvtArgs {
  const float* src[5];
  bf16* dst[5];
  int n[5];
};
__global__ __launch_bounds__(256) void cvt_f2b_multi(CvtArgs a) {
  const int z = blockIdx.y;
  const int idx = (blockIdx.x * 256 + threadIdx.x) * 8;
  if (idx >= a.n[z]) return;
  const float* src = a.src[z];
  s16x8 o;
#pragma unroll
  for (int i = 0; i < 8; ++i) o[i] = f2b(src[idx + i]);
  *(s16x8*)(a.dst[z] + idx) = o;
}

// ---------------------------------------------------------------------------
// MFMA NT GEMM: C[m,n] = sum_k A[m,k]*W[n,k] + bias[n]  (bias fp32)
// 128x128 tile, 4 waves (2x2), 4x4 16x16x32 frags.
// v8: 2-buffer gl_lds, one __syncthreads drain per K-step; 1D T1 XCD chunk.
//     BK=64 now for MODE 1 TOO (round-11: MLP1 regressed to 68 us at BK=32,
//     drain-count 32 is the latency multiplier; BK=64 halves it to 16 —
//     same cure as MODE 0/2/4, precedent MODE 2 sustains 1.85 TB/s @ 2/CU).
//     Only MODE 3 (QKV) remains BK=32 (grid 768, 3/CU TLP).
// MODE 1: relu, C -> bf16 Cb       (MLP1 -> ff)               [BK=64]
// MODE 2: SPLIT-K=2. z=0: K-half-0 + bias + resid -> fp32 Cf;
//         z=1: raw -> fp32 Kf (rows<2048) / Vf (rows>=2048).  [BK=64]
// MODE 3: QKV split: seg0 q*0.125 -> bf16 Cb; seg1 k->fp32 Kf + bf16 Kb;
//         seg2 v->fp32 Vf + bf16 Vb.                          [BK=32]
// MODE 4: out-proj SPLIT-K=2: z=0: K-half-0 + bias -> Cf;
//         z=1: raw K-half-1 -> Kf. LN1 sums Cf+Kf.            [BK=64]
// ---------------------------------------------------------------------------
template <int MODE>
__global__ __launch_bounds__(256) void gemm_bt(
    const bf16* __restrict__ A, const bf16* __restrict__ W,
    const float* __restrict__ bias,
    bf16* __restrict__ Cb, float* __restrict__ Cf,
    float* __restrict__ Kf, bf16* __restrict__ Kb,
    float* __restrict__ Vf, bf16* __restrict__ Vb,
    const bf16* __restrict__ Res,
    int M, int N, int K) {
  constexpr int BK = (MODE == 3) ? 32 : 64;
  constexpr bool SPLITK = (MODE == 2 || MODE == 4);
  __shared__ __align__(16) bf16 As[2][128 * BK];
  __shared__ __align__(16) bf16 Bs[2][128 * BK];
  const int t = threadIdx.x;

  // 1D T1 XCD-chunked swizzle (nwg % 8 == 0 -> bijective).
  const int bid = blockIdx.y * gridDim.x + blockIdx.x;
  const int nwg = gridDim.x * gridDim.y;
  const int sw  = (bid & 7) * (nwg >> 3) + (bid >> 3);
  const int m0 = (sw / gridDim.x) << 7, n0 = (sw % gridDim.x) << 7;

  const int w = t >> 6, l = t & 63;
  const int wm = (w >> 1) << 6, wn = (w & 1) << 6;
  const int l15 = l & 15, quad = l >> 4;

  const int kz   = SPLITK ? (int)blockIdx.z : 0;   // K-split index
  const int Keff = SPLITK ? (K >> 1) : K;

  f32x4 acc[4][4] = {};

  // staging addresses
  const int srow = (BK == 32) ? (t >> 2) : (t >> 3);
  const int scol = (BK == 32) ? ((t & 3) << 3)
                              : (((t & 7) ^ ((t >> 3) & 7)) << 3);  // pre-swz
  const bf16* Ag  = A + (size_t)(m0 + srow) * K + kz * Keff + scol;
  const bf16* Ag2 = Ag + ((size_t)K << 6);   // +64 rows (BK=32 path)
  const bf16* Wg  = W + (size_t)(n0 + srow) * K + kz * Keff + scol;
  const bf16* Wg2 = Wg + ((size_t)K << 6);

#define STAGE_G(KI, BUF) do {                                                \
    if constexpr (BK == 32) {                                                \
      const int ko_ = (KI) * 32;                                             \
      gl_lds16(Ag + ko_, (bf16*)As[BUF] + t * 8);                            \
      gl_lds16(Ag2 + ko_, (bf16*)As[BUF] + 2048 + t * 8);                    \
      gl_lds16(Wg + ko_, (bf16*)Bs[BUF] + t * 8);                            \
      gl_lds16(Wg2 + ko_, (bf16*)Bs[BUF] + 2048 + t * 8);                    \
    } else {                                                                 \
      const int ko_ = (KI) * 64;                                             \
      _Pragma("unroll") for (int i_ = 0; i_ < 4; ++i_) {                     \
        gl_lds16(Ag + ko_ + (size_t)32 * K * i_,                             \
                 (bf16*)As[BUF] + i_ * 2048 + t * 8);                        \
        gl_lds16(Wg + ko_ + (size_t)32 * K * i_,                             \
                 (bf16*)Bs[BUF] + i_ * 2048 + t * 8);                        \
      }                                                                      \
    }                                                                        \
  } while (0)

  const int nk = Keff / BK;
  STAGE_G(0, 0);
  __syncthreads();

  for (int ki = 0; ki < nk; ++ki) {
    const int cur = ki & 1;
    if (ki + 1 < nk) STAGE_G(ki + 1, cur ^ 1);

    const s16x8* As8 = (const s16x8*)As[cur];
    const s16x8* Bs8 = (const s16x8*)Bs[cur];
    if constexpr (BK == 32) {
      s16x8 af[4], bfr[4];
#pragma unroll
      for (int i = 0; i < 4; ++i) af[i]  = As8[((wm + i * 16 + l15) << 2) + quad];
#pragma unroll
      for (int i = 0; i < 4; ++i) bfr[i] = Bs8[((wn + i * 16 + l15) << 2) + quad];
      __builtin_amdgcn_s_setprio(1);
#pragma unroll
      for (int mi = 0; mi < 4; ++mi)
#pragma unroll
        for (int ni = 0; ni < 4; ++ni)
          acc[mi][ni] = mfma_bf16(af[mi], bfr[ni], acc[mi][ni]);
      __builtin_amdgcn_s_setprio(0);
    } else {
      const int sx = l15 & 7;
#pragma unroll
      for (int h = 0; h < 2; ++h) {
        s16x8 af[4], bfr[4];
#pragma unroll
        for (int i = 0; i < 4; ++i)
          af[i]  = As8[((wm + i * 16 + l15) << 3) + ((h * 4 + quad) ^ sx)];
#pragma unroll
        for (int i = 0; i < 4; ++i)
          bfr[i] = Bs8[((wn + i * 16 + l15) << 3) + ((h * 4 + quad) ^ sx)];
        __builtin_amdgcn_s_setprio(1);
#pragma unroll
        for (int mi = 0; mi < 4; ++mi)
#pragma unroll
          for (int ni = 0; ni < 4; ++ni)
            acc[mi][ni] = mfma_bf16(af[mi], bfr[ni], acc[mi][ni]);
        __builtin_amdgcn_s_setprio(0);
      }
    }
    __syncthreads();
  }
#undef STAGE_G

  float bv[4];
#pragma unroll
  for (int ni = 0; ni < 4; ++ni)
    bv[ni] = bias[n0 + wn + ni * 16 + l15];

  const int seg = n0 >> 10, nb2 = n0 & 1023;
#pragma unroll
  for (int mi = 0; mi < 4; ++mi) {
#pragma unroll
    for (int reg = 0; reg < 4; ++reg) {
      const int row = m0 + wm + mi * 16 + quad * 4 + reg;
#pragma unroll
      for (int ni = 0; ni < 4; ++ni) {
        float v = acc[mi][ni][reg] + ((SPLITK && kz) ? 0.f : bv[ni]);
        if (MODE == 1) {
          v = fmaxf(v, 0.f);
          Cb[(size_t)row * N + n0 + wn + ni * 16 + l15] = __float2bfloat16(v);
        } else if (MODE == 2) {
          const size_t col = n0 + wn + ni * 16 + l15;
          if (kz == 0) {
            const size_t o = (size_t)row * N + col;
            Cf[o] = v + b2f(*(const short*)&Res[o]);
          } else {
            float* P = (row < 2048) ? Kf : Vf;   // partial bufs (dead ws)
            P[(size_t)(row & 2047) * N + col] = v;
          }
        } else if (MODE == 4) {
          const size_t o = (size_t)row * N + n0 + wn + ni * 16 + l15;
          if (kz == 0) Cf[o] = v;            // bias + K-half-0
          else         Kf[o] = v;            // raw K-half-1
        } else {  // MODE 3
          const size_t o = (size_t)row * 1024 + nb2 + wn + ni * 16 + l15;
          if (seg == 0) {
            Cb[o] = __float2bfloat16(v * 0.125f);   // pre-scale Q by 1/sqrt(hd)
          } else if (seg == 1) {
            Kf[o] = v; Kb[o] = __float2bfloat16(v);
          } else {
            Vf[o] = v; Vb[o] = __float2bfloat16(v);
          }
        }
      }
    }
  }
}

// ---------------------------------------------------------------------------
// MFMA flash attention v7, causal, hd=64.  (unchanged from round 10)
// 3-buffer K/V, single barrier per tile; XCD-locality decode; cheap
// defer-max gate; setprio. Verified: FETCH 12.4 MB, ~44 us.
// ---------------------------------------------------------------------------
#define BAR_SYNC() do {                                                      \
    asm volatile("s_waitcnt lgkmcnt(0)" ::: "memory");                       \
    __builtin_amdgcn_s_barrier();                                            \
    __builtin_amdgcn_sched_barrier(0);                                       \
  } while (0)

#define ISSUE(KT) do { const size_t ko_ = (size_t)((KT) << 6) * D_;          \
    kr0 = *(const s16x8*)(Kg + ko_);                                         \
    kr1 = *(const s16x8*)(Kg2 + ko_);                                        \
    vr0 = *(const s16x8*)(Vg + ko_);                                         \
    vr1 = *(const s16x8*)(Vg + ko_ + 8);                                     \
  } while (0)

#define WRITEKV(BUFI) do {                                                   \
    bf16* kd_ = Ks[BUFI];                                                    \
    *(s16x8*)&kd_[krow * 64 + (kchunk << 3)] = kr0;                          \
    *(s16x8*)&kd_[(krow + 32) * 64 + (kchunk << 3)] = kr1;                   \
    short* vp_ = (short*)Vt[BUFI];                                           \
    _Pragma("unroll") for (int j = 0; j < 8; ++j) {                          \
      const int d0_ = vd + j, d1_ = vd + 8 + j;                              \
      vp_[d0_ * 64 + (vk ^ ((d0_ & 7) << 3))] = vr0[j];                      \
      vp_[d1_ * 64 + (vk ^ ((d1_ & 7) << 3))] = vr1[j];                      \
    }                                                                        \
  } while (0)

#define QK_LOAD(BUFI) do { const bf16* Kq_ = Ks[BUFI];                       \
    ka0 = *(const s16x8*)&Kq_[( 0 + l15) * 64 + (( 0 + quad * 8) ^ swr)];    \
    ka1 = *(const s16x8*)&Kq_[(16 + l15) * 64 + (( 0 + quad * 8) ^ swr)];    \
    ka2 = *(const s16x8*)&Kq_[(32 + l15) * 64 + (( 0 + quad * 8) ^ swr)];    \
    ka3 = *(const s16x8*)&Kq_[(48 + l15) * 64 + (( 0 + quad * 8) ^ swr)];    \
    kb0 = *(const s16x8*)&Kq_[( 0 + l15) * 64 + ((32 + quad * 8) ^ swr)];    \
    kb1 = *(const s16x8*)&Kq_[(16 + l15) * 64 + ((32 + quad * 8) ^ swr)];    \
    kb2 = *(const s16x8*)&Kq_[(32 + l15) * 64 + ((32 + quad * 8) ^ swr)];    \
    kb3 = *(const s16x8*)&Kq_[(48 + l15) * 64 + ((32 + quad * 8) ^ swr)];    \
  } while (0)

#define QK_MFMA(S0_, S1_, S2_, S3_) do {                                     \
    __builtin_amdgcn_s_setprio(1);                                           \
    f32x4 z_ = {};                                                           \
    z_ = mfma_bf16(qf0, ka0, z_); S0_ = mfma_bf16(qf1, kb0, z_);             \
    z_ = (f32x4){};                                                          \
    z_ = mfma_bf16(qf0, ka1, z_); S1_ = mfma_bf16(qf1, kb1, z_);             \
    z_ = (f32x4){};                                                          \
    z_ = mfma_bf16(qf0, ka2, z_); S2_ = mfma_bf16(qf1, kb2, z_);             \
    z_ = (f32x4){};                                                          \
    z_ = mfma_bf16(qf0, ka3, z_); S3_ = mfma_bf16(qf1, kb3, z_);             \
    __builtin_amdgcn_s_setprio(0);                                           \
  } while (0)

#define SMAXPV(J, BUFI, S0_, S1_, S2_, S3_) do {                             \
    if ((J) == nt - 1) {  /* diagonal tile only */                           \
      _Pragma("unroll") for (int reg = 0; reg < 4; ++reg) {                  \
        const int qrow_ = qb + (w << 4) + quad * 4 + reg;                    \
        const int k0_ = ((J) << 6) + l15;                                    \
        if (k0_ +  0 > qrow_) S0_[reg] = -1e30f;                             \
        if (k0_ + 16 > qrow_) S1_[reg] = -1e30f;                             \
        if (k0_ + 32 > qrow_) S2_[reg] = -1e30f;                             \
        if (k0_ + 48 > qrow_) S3_[reg] = -1e30f;                             \
      }                                                                      \
    }                                                                        \
    float lm_[4];  /* lane-local max only (cheap defer-max gate) */          \
    _Pragma("unroll") for (int reg = 0; reg < 4; ++reg)                      \
      lm_[reg] = fmaxf(fmaxf(S0_[reg], S1_[reg]), fmaxf(S2_[reg], S3_[reg]));\
    bool up_ = false;                                                        \
    _Pragma("unroll") for (int reg = 0; reg < 4; ++reg)                      \
      up_ = up_ || (lm_[reg] > m_i[reg] + 8.f);                              \
    if (__any(up_)) {  /* rare: full reduce + rescale (T13) */               \
      float mx_[4];                                                          \
      _Pragma("unroll") for (int reg = 0; reg < 4; ++reg) mx_[reg] = lm_[reg];\
      _Pragma("unroll") for (int off = 1; off < 16; off <<= 1)               \
        _Pragma("unroll") for (int reg = 0; reg < 4; ++reg)                  \
          mx_[reg] = fmaxf(mx_[reg], __shfl_xor(mx_[reg], off, 64));         \
      _Pragma("unroll") for (int reg = 0; reg < 4; ++reg) {                  \
        const float nm_ = fmaxf(m_i[reg], mx_[reg]);                         \
        const float al_ = __expf(m_i[reg] - nm_);                            \
        m_i[reg] = nm_; l_p[reg] *= al_;                                     \
        o[0][reg] *= al_; o[1][reg] *= al_;                                  \
        o[2][reg] *= al_; o[3][reg] *= al_;                                  \
      }                                                                      \
    }                                                                        \
    _Pragma("unroll") for (int reg = 0; reg < 4; ++reg) {                    \
      const float e0_ = __expf(S0_[reg] - m_i[reg]);                         \
      const float e1_ = __expf(S1_[reg] - m_i[reg]);                         \
      const float e2_ = __expf(S2_[reg] - m_i[reg]);                         \
      const float e3_ = __expf(S3_[reg] - m_i[reg]);                         \
      l_p[reg] += e0_ + e1_ + e2_ + e3_;                                     \
      const int row_ = quad * 4 + reg;                                       \
      bf16* pr_ = &Ps[w][row_ * 64];                                         \
      const int sx_ = (row_ & 7) << 3;                                       \
      pr_[( 0 + l15) ^ sx_] = __float2bfloat16(e0_);                         \
      pr_[(16 + l15) ^ sx_] = __float2bfloat16(e1_);                         \
      pr_[(32 + l15) ^ sx_] = __float2bfloat16(e2_);                         \
      pr_[(48 + l15) ^ sx_] = __float2bfloat16(e3_);                         \
    }                                                                        \
    {                                                                        \
      const bf16* Vc_ = Vt[BUFI];                                            \
      _Pragma("unroll") for (int ks = 0; ks < 2; ++ks) {                     \
        const s16x8 pf_ =                                                    \
            *(const s16x8*)&Ps[w][l15 * 64 + ((ks * 32 + quad * 8) ^ swr)];  \
        __builtin_amdgcn_s_setprio(1);                                       \
        _Pragma("unroll") for (int ni = 0; ni < 4; ++ni) {                   \
          const s16x8 vf_ = *(const s16x8*)                                  \
              &Vc_[(ni * 16 + l15) * 64 + ((ks * 32 + quad * 8) ^ swr)];     \
          o[ni] = mfma_bf16(pf_, vf_, o[ni]);                                \
        }                                                                    \
        __builtin_amdgcn_s_setprio(0);                                       \
      }                                                                      \
    }                                                                        \
  } while (0)

// One barrier per tile; 3-buffer rotation handled by bq/bw/bvb variables.
#define BODY(KT, SO0, SO1, SO2, SO3, SN0, SN1, SN2, SN3) do {                \
    BAR_SYNC();                                                              \
    if ((KT) + 1 < nt) ISSUE((KT) + 1);                                      \
    QK_LOAD(bq);                                                             \
    QK_MFMA(SN0, SN1, SN2, SN3);                                             \
    SMAXPV((KT) - 1, bvb, SO0, SO1, SO2, SO3);                               \
    if ((KT) + 1 < nt) WRITEKV(bw);                                          \
    bvb = bq; bq = bw; bw = (bw == 2) ? 0 : bw + 1;                          \
  } while (0)

__global__ __launch_bounds__(256, 2) void flash_attn(
    const bf16* __restrict__ Q, const bf16* __restrict__ Kk,
    const bf16* __restrict__ V, bf16* __restrict__ O) {
  // XCD-locality decode: all 16 pair-blocks of one (h,b) -> same XCD.
  const int lin = (int)(blockIdx.x + 16 * blockIdx.y + 256 * blockIdx.z);
  const int xcd = lin & 7;
  const int slot = lin >> 3;                  // 0..63
  const int bxp = slot >> 2;                  // 0..15: q-tile pair id
  const int g = xcd + ((slot & 3) << 3);      // 0..31: (h,b) group
  const int h = g & 15, b = g >> 4;

  const int t = threadIdx.x, w = t >> 6, l = t & 63;
  const int l15 = l & 15, quad = l >> 4;
  __shared__ __align__(16) bf16 Ks[3][64 * 64];    // [buf][key][d] swizzled
  __shared__ __align__(16) bf16 Vt[3][64 * 64];    // [buf][d][key] swizzled
  __shared__ __align__(16) bf16 Ps[4][16 * 64];    // per-wave P, swizzled

  // K staging: linear global chunk; swizzle applied at ds_write dest.
  const int krow = t >> 3;                    // 0..31
  const int kchunk = (t & 7) ^ (krow & 7);    // swizzled LDS chunk
  const bf16* Kg  = Kk + (size_t)(b * S_ + krow) * D_ + h * HD_ + ((t & 7) << 3);
  const bf16* Kg2 = Kg + (size_t)32 * D_;
  const int vk = t & 63, vd = w << 4;
  const bf16* Vg = V + (size_t)(b * S_ + vk) * D_ + h * HD_ + vd;
  const int swr = (l15 & 7) << 3;             // read-side xor (elements)

  s16x8 kr0, kr1, vr0, vr1;                   // staging regs (1 tile)
  s16x8 ka0, ka1, ka2, ka3, kb0, kb1, kb2, kb3;  // K fragment regs

#pragma unroll 1
  for (int ph = 0; ph < 2; ++ph) {
    const int qt = ph ? (S_ / 64 - 1 - bxp) : bxp;
    const int qb = qt << 6;
    const int nt = qt + 1;

    __syncthreads();   // protect LDS reuse across phases

    const bf16* qp =
        Q + (size_t)(b * S_ + qb + (w << 4) + l15) * D_ + h * HD_ + quad * 8;
    const s16x8 qf0 = *(const s16x8*)qp;
    const s16x8 qf1 = *(const s16x8*)(qp + 32);

    f32x4 o[4] = {};
    float m_i[4], l_p[4];
#pragma unroll
    for (int r = 0; r < 4; ++r) { m_i[r] = -1e30f; l_p[r] = 0.f; }

    f32x4 sA0, sA1, sA2, sA3, sB0, sB1, sB2, sB3;
    int bq = 1, bw = 2, bvb = 0;   // buf(KT)%3 rotation state (for KT=1)

    // ---- prologue: tile 0 ----
    ISSUE(0);
    WRITEKV(0);                  // counted vmcnt waits for kr/vr (cold, once)
    BAR_SYNC();
    if (nt > 1) ISSUE(1);
    QK_LOAD(0);
    QK_MFMA(sA0, sA1, sA2, sA3);
    if (nt > 1) WRITEKV(1);

    // ---- main loop: 1 barrier/tile, ping-pong score regs ----
    int kt = 1;
    for (; kt + 1 < nt; kt += 2) {
      BODY(kt,     sA0, sA1, sA2, sA3, sB0, sB1, sB2, sB3);
      BODY(kt + 1, sB0, sB1, sB2, sB3, sA0, sA1, sA2, sA3);
    }
    if (kt < nt) {
      BODY(kt, sA0, sA1, sA2, sA3, sB0, sB1, sB2, sB3);
      SMAXPV(nt - 1, bvb, sB0, sB1, sB2, sB3);
    } else {
      SMAXPV(nt - 1, bvb, sA0, sA1, sA2, sA3);
    }

    // ---- epilogue: deferred l reduction + O write ----
    float inv[4];
#pragma unroll
    for (int off = 1; off < 16; off <<= 1)
#pragma unroll
      for (int reg = 0; reg < 4; ++reg)
        l_p[reg] += __shfl_xor(l_p[reg], off, 64);
#pragma unroll
    for (int reg = 0; reg < 4; ++reg) inv[reg] = 1.f / l_p[reg];

#pragma unroll
    for (int reg = 0; reg < 4; ++reg) {
      const int row = b * S_ + qb + (w << 4) + quad * 4 + reg;
      bf16* op = O + (size_t)row * D_ + h * HD_ + l15;
#pragma unroll
      for (int ni = 0; ni < 4; ++ni)
        op[ni * 16] = __float2bfloat16(o[ni][reg] * inv[reg]);
    }
  }
}

// ---------------------------------------------------------------------------
// LN1 (MODE 0): h1 = LN(x_f32 + P0 + P1) -> bf16  (P0/P1 = out-proj K-half
//               fp32 partials; P0 carries the bias).
// LN2 (MODE 1): out = LN(X + PA/PB row-split partial) -> fp32 in place.
// One block per 1024-col row.
// ---------------------------------------------------------------------------
template <int MODE>   // 0: LN1, 1: LN2
__global__ __launch_bounds__(256) void add_ln(
    const float* __restrict__ X,
    const float* __restrict__ PA, const float* __restrict__ PB,
    const float* __restrict__ g, const float* __restrict__ be,
    void* Out) {
  const int row = blockIdx.x, t = threadIdx.x;
  const size_t base = (size_t)row * D_ + t * 4;
  const float* P = (MODE == 1)
      ? ((row < 2048) ? PA + base : PB + (base - (size_t)2048 * D_))
      : nullptr;
  float v[4];
  float s = 0.f, q = 0.f;
#pragma unroll
  for (int i = 0; i < 4; ++i) {
    v[i] = X[base + i];
    if (MODE == 0) v[i] += PA[base + i] + PB[base + i];
    else           v[i] += P[i];
    s += v[i];
    q += v[i] * v[i];
  }
#pragma unroll
  for (int off = 32; off; off >>= 1) {
    s += __shfl_down(s, off, 64);
    q += __shfl_down(q, off, 64);
  }
  __shared__ float rs[4], rq[4];
  const int w = t >> 6, l = t & 63;
  if (l == 0) { rs[w] = s; rq[w] = q; }
  __syncthreads();
  s = rs[0] + rs[1] + rs[2] + rs[3];
  q = rq[0] + rq[1] + rq[2] + rq[3];
  const float mu = s * (1.f / D_);
  const float var = q * (1.f / D_) - mu * mu;
  const float rstd = rsqrtf(var + 1e-5f);
#pragma unroll
  for (int i = 0; i < 4; ++i) {
    const float r = (v[i] - mu) * rstd * g[t * 4 + i] + be[t * 4 + i];
    if (MODE == 0) ((bf16*)Out)[base + i] = __float2bfloat16(r);
    else           ((float*)Out)[base + i] = r;
  }
}

extern "C" void kernel_launch(void* const* d_in, const int* in_sizes, int n_in,
                              void* d_out, int out_size, void* d_ws, size_t ws_size,
                              hipStream_t stream) {
  const float* x     = (const float*)d_in[0];
  const float* qkv_b = (const float*)d_in[2];
  const float* out_b = (const float*)d_in[4];
  const float* b1    = (const float*)d_in[6];
  const float* b2    = (const float*)d_in[8];
  const float* l1w   = (const float*)d_in[9];
  const float* l1b   = (const float*)d_in[10];
  const float* l2w   = (const float*)d_in[11];
  const float* l2b   = (const float*)d_in[12];

  float* out    = (float*)d_out;
  float* kcache = out + (size_t)M_ * D_;
  float* vcache = kcache + (size_t)M_ * D_;

  // ws (bf16 elems). High-water 36M elems = 72 MB (<75 MB established safe).
  //  [0,4M)   xc -> attnb (after QKV) -> pA fp32 MLP2 partial (after LN1)
  //  [4,7M)   wqkv -> h1 (after out-proj; h1 spans [4,8M))
  //  [7,8M)   wout
  //  [8,12M)  w1c
  //  [12,16M) w2c
  //  [16,20M) qbuf (dead after flash) -> pB fp32 MLP2 partial
  //  [20,24M) kb;  [24,28M) vb  (dead after flash)
  //  [20,28M) oP0 fp32 out-proj partial 0 (after flash)
  //  [28,36M) oP1 fp32 out-proj partial 1
  //  [20,36M) ffb (after LN1)
  bf16* ws    = (bf16*)d_ws;
  bf16* xc    = ws;
  bf16* attnb = ws;
  bf16* wqkv  = ws + 4 * MEG;
  bf16* h1    = ws + 4 * MEG;
  bf16* wout  = ws + 7 * MEG;
  bf16* w1c   = ws + 8 * MEG;
  bf16* w2c   = ws + 12 * MEG;
  bf16* qbuf  = ws + 16 * MEG;
  bf16* kb    = ws + 20 * MEG;
  bf16* ffb   = ws + 20 * MEG;
  bf16* vb    = ws + 24 * MEG;
  float* oP0  = (float*)(ws + 20 * MEG);  // out-proj K-half-0 + bias
  float* oP1  = (float*)(ws + 28 * MEG);  // out-proj K-half-1 raw
  float* pA   = (float*)ws;               // MLP2 rows 0..2047 partial
  float* pB   = (float*)(ws + 16 * MEG);  // MLP2 rows 2048..4095 partial

  const dim3 blk(256);

  // all 5 fp32->bf16 conversions in one dispatch
  CvtArgs ca;
  ca.src[0] = x;                    ca.dst[0] = xc;   ca.n[0] = M_ * D_;
  ca.src[1] = (const float*)d_in[1]; ca.dst[1] = wqkv; ca.n[1] = 3 * D_ * D_;
  ca.src[2] = (const float*)d_in[3]; ca.dst[2] = wout; ca.n[2] = D_ * D_;
  ca.src[3] = (const float*)d_in[5]; ca.dst[3] = w1c;  ca.n[3] = FFD_ * D_;
  ca.src[4] = (const float*)d_in[7]; ca.dst[4] = w2c;  ca.n[4] = D_ * FFD_;
  cvt_f2b_multi<<<dim3((M_ * D_ + 2047) / 2048, 5), blk, 0, stream>>>(ca);

  // QKV: q (pre-scaled 0.125) -> qbuf bf16; k/v->fp32 caches + bf16 ws copies.
  gemm_bt<3><<<dim3(3 * D_ / 128, M_ / 128), blk, 0, stream>>>(
      xc, wqkv, qkv_b, qbuf, nullptr, kcache, kb, vcache, vb, nullptr,
      M_, 3 * D_, D_);
  flash_attn<<<dim3(S_ / 128, H_, B_), blk, 0, stream>>>(qbuf, kb, vb, attnb);
  // out-proj SPLIT-K=2: z=0 bias + K-half-0 -> oP0; z=1 raw -> oP1.
  gemm_bt<4><<<dim3(D_ / 128, M_ / 128, 2), blk, 0, stream>>>(
      attnb, wout, out_b, nullptr, oP0, oP1, nullptr, nullptr, nullptr,
      nullptr, M_, D_, D_);
  // h1 = LN(x + oP0 + oP1) -> bf16 (overwrites dead wqkv)
  add_ln<0><<<dim3(M_), blk, 0, stream>>>(x, oP0, oP1, l1w, l1b, h1);
  // MLP full-M: MLP1 (BK=64) -> ffb [20,36M); MLP2 split-K=2 + BK=64:
  // z=0 K-half-0 + bias + resid -> out; z=1 K-half-1 raw -> pA/pB.
  gemm_bt<1><<<dim3(FFD_ / 128, M_ / 128), blk, 0, stream>>>(
      h1, w1c, b1, ffb, nullptr, nullptr, nullptr, nullptr, nullptr,
      nullptr, M_, FFD_, D_);
  gemm_bt<2><<<dim3(D_ / 128, M_ / 128, 2), blk, 0, stream>>>(
      ffb, w2c, b2, nullptr, out, pA, nullptr, pB, nullptr,
      h1, M_, D_, FFD_);
  // out = LN(out + partial) in place, fp32.
  add_ln<1><<<dim3(M_), blk, 0, stream>>>(out, pA, pB, l2w, l2b, out);
}